// Round 7
// baseline (934.922 us; speedup 1.0000x reference)
//
#include <hip/hip_runtime.h>
#include <hip/hip_bf16.h>

// MHSA: B=16, C=256, H=W=48, N=2304.
// S[b,n,m] = q[b,:,n]·k[b,:,m] + rhq[b][n%48][m] + rwq[b][n/48][m]
//   rhq = rel_h^T q, rwq = rel_w^T q  (rank-split of the pos term, fp32)
// att = softmax_m(S); out[b,c,n] = sum_m v[b,c,m] att[n,m]
// fp32 accuracy for logits via split-bf16 (hi+lo, 3 MFMA passes).
//
// R6 lesson: V-in-LDS fixed the PV latency chain (965->437us). Remaining:
// load imbalance — 288 blocks @ 2/CU capacity -> 32 CUs run 2 blocks, 224 idle
// half the time (Occ 13%). R7: 256 blocks x 9 waves x 16 rows (144 rows/block),
// exactly 1 block/CU, perfectly balanced. Staging by waves 0-7 only.

#define BB 16
#define CC 256
#define HH 48
#define NN 2304

typedef float f32x4 __attribute__((ext_vector_type(4)));
typedef short bf16x8 __attribute__((ext_vector_type(8)));

#define MFMA(a, b, c) __builtin_amdgcn_mfma_f32_16x16x32_bf16((a), (b), (c), 0, 0, 0)

__device__ inline bf16x8 ldg8(const __hip_bfloat16* p) {
    return *reinterpret_cast<const bf16x8*>(p);
}

typedef __attribute__((address_space(3))) unsigned int lds_uint;
typedef const __attribute__((address_space(1))) unsigned int gbl_uint;

__device__ inline void gload_lds16(const __hip_bfloat16* g, __hip_bfloat16* l) {
    __builtin_amdgcn_global_load_lds((gbl_uint*)g, (lds_uint*)l, 16, 0, 0);
}

// ---- prep: transpose x [b][c][n] -> xT [b][n][c], split into bf16 hi/lo ----
__global__ __launch_bounds__(256) void k_prep_x(const float* __restrict__ x,
        __hip_bfloat16* __restrict__ xt_hi, __hip_bfloat16* __restrict__ xt_lo) {
    __shared__ float tile[64][65];
    int b = blockIdx.z, n0 = blockIdx.x * 64, c0 = blockIdx.y * 64;
    const float* xb = x + (size_t)b * CC * NN;
    #pragma unroll
    for (int i = 0; i < 16; ++i) {
        int idx = i * 256 + threadIdx.x;
        int r = idx >> 6, col = idx & 63;
        tile[r][col] = xb[(size_t)(c0 + r) * NN + n0 + col];
    }
    __syncthreads();
    #pragma unroll
    for (int i = 0; i < 16; ++i) {
        int idx = i * 256 + threadIdx.x;
        int r = idx >> 6, col = idx & 63;           // r = n-local, col = c-local
        float v = tile[col][r];
        __hip_bfloat16 h = __float2bfloat16(v);
        size_t o = ((size_t)b * NN + n0 + r) * CC + c0 + col;
        xt_hi[o] = h;
        xt_lo[o] = __float2bfloat16(v - __bfloat162float(h));
    }
}

// ---- prep: split Wq/Wk/Wv into hi/lo (layout [3][256][256] row-major) ----
__global__ __launch_bounds__(256) void k_prep_w(const float* __restrict__ Wq,
        const float* __restrict__ Wk, const float* __restrict__ Wv,
        __hip_bfloat16* __restrict__ w_hi, __hip_bfloat16* __restrict__ w_lo) {
    int i = blockIdx.x * 256 + threadIdx.x;         // < 3*65536
    int m = i >> 16, j = i & 65535;
    const float* W = (m == 0) ? Wq : ((m == 1) ? Wk : Wv);
    float v = W[j];
    __hip_bfloat16 h = __float2bfloat16(v);
    w_hi[i] = h;
    w_lo[i] = __float2bfloat16(v - __bfloat162float(h));
}

// ---- prep: relhT[h][c] = rel_h[c][h], relwT[w][c] = rel_w[c][w], hi/lo split
__global__ __launch_bounds__(256) void k_prep_rel(const float* __restrict__ rel_h,
        const float* __restrict__ rel_w,
        __hip_bfloat16* __restrict__ relhT_hi, __hip_bfloat16* __restrict__ relhT_lo,
        __hip_bfloat16* __restrict__ relwT_hi, __hip_bfloat16* __restrict__ relwT_lo) {
    int i = blockIdx.x * 256 + threadIdx.x;         // < 48*256
    int h = i >> 8, c = i & 255;
    float vh = rel_h[c * HH + h];
    float vw = rel_w[c * HH + h];
    __hip_bfloat16 hh = __float2bfloat16(vh);
    relhT_hi[i] = hh;
    relhT_lo[i] = __float2bfloat16(vh - __bfloat162float(hh));
    __hip_bfloat16 hw = __float2bfloat16(vw);
    relwT_hi[i] = hw;
    relwT_lo[i] = __float2bfloat16(vw - __bfloat162float(hw));
}

// ---- projection GEMM: yT[b][n][o] = sum_c xT[b][n][c] * W[o][c] + bias[o] ----
// pj=0 -> qT hi/lo, pj=1 -> kT hi/lo, pj=2 -> v[b][o][n] bf16
__global__ __launch_bounds__(256) void k_proj(
        const __hip_bfloat16* __restrict__ xt_hi, const __hip_bfloat16* __restrict__ xt_lo,
        const __hip_bfloat16* __restrict__ w_hi,  const __hip_bfloat16* __restrict__ w_lo,
        const float* __restrict__ bq, const float* __restrict__ bk, const float* __restrict__ bv,
        __hip_bfloat16* __restrict__ qt_hi, __hip_bfloat16* __restrict__ qt_lo,
        __hip_bfloat16* __restrict__ kt_hi, __hip_bfloat16* __restrict__ kt_lo,
        __hip_bfloat16* __restrict__ vbuf) {
    int b = blockIdx.y, pj = blockIdx.z;
    int n0 = (blockIdx.x >> 2) * 64, o0 = (blockIdx.x & 3) * 64;
    int wave = threadIdx.x >> 6, lane = threadIdx.x & 63;
    int lr = lane & 15, lg = lane >> 4;
    int rowA = n0 + wave * 16 + lr;
    const __hip_bfloat16* wh = w_hi + (size_t)pj * 65536;
    const __hip_bfloat16* wl = w_lo + (size_t)pj * 65536;
    const __hip_bfloat16* axh = xt_hi + ((size_t)b * NN + rowA) * CC;
    const __hip_bfloat16* axl = xt_lo + ((size_t)b * NN + rowA) * CC;
    f32x4 acc[4] = {};
    #pragma unroll
    for (int ks = 0; ks < 8; ++ks) {
        int kk = ks * 32 + lg * 8;
        bf16x8 ah = ldg8(axh + kk);
        bf16x8 al = ldg8(axl + kk);
        #pragma unroll
        for (int ot = 0; ot < 4; ++ot) {
            int rowB = o0 + ot * 16 + lr;
            bf16x8 bh = ldg8(wh + rowB * CC + kk);
            bf16x8 bl = ldg8(wl + rowB * CC + kk);
            acc[ot] = MFMA(ah, bh, acc[ot]);
            acc[ot] = MFMA(ah, bl, acc[ot]);
            acc[ot] = MFMA(al, bh, acc[ot]);
        }
    }
    const float* bias = (pj == 0) ? bq : ((pj == 1) ? bk : bv);
    #pragma unroll
    for (int ot = 0; ot < 4; ++ot) {
        int o = o0 + ot * 16 + lr;
        float bb = bias[o];
        #pragma unroll
        for (int r = 0; r < 4; ++r) {
            int n = n0 + wave * 16 + lg * 4 + r;
            float y = acc[ot][r] + bb;
            if (pj == 0) {
                __hip_bfloat16 h = __float2bfloat16(y);
                size_t off = ((size_t)b * NN + n) * CC + o;
                qt_hi[off] = h;
                qt_lo[off] = __float2bfloat16(y - __bfloat162float(h));
            } else if (pj == 1) {
                __hip_bfloat16 h = __float2bfloat16(y);
                size_t off = ((size_t)b * NN + n) * CC + o;
                kt_hi[off] = h;
                kt_lo[off] = __float2bfloat16(y - __bfloat162float(h));
            } else {
                vbuf[((size_t)b * CC + o) * NN + n] = __float2bfloat16(y);
            }
        }
    }
}

// ---- pos rank-split: rhq[b][h][m] = sum_c relhT[h][c] q[b][c][m]; same for rwq
__global__ __launch_bounds__(256) void k_posq(
        const __hip_bfloat16* __restrict__ qt_hi, const __hip_bfloat16* __restrict__ qt_lo,
        const __hip_bfloat16* __restrict__ relhT_hi, const __hip_bfloat16* __restrict__ relhT_lo,
        const __hip_bfloat16* __restrict__ relwT_hi, const __hip_bfloat16* __restrict__ relwT_lo,
        float* __restrict__ rhq, float* __restrict__ rwq) {
    int b = blockIdx.y, m0 = blockIdx.x * 64;
    int wave = threadIdx.x >> 6, lane = threadIdx.x & 63;
    int lr = lane & 15, lg = lane >> 4;
    int m = m0 + wave * 16 + lr;                    // output column
    const size_t bN = (size_t)b * NN;
    f32x4 acc[6] = {};                              // 3 h-tiles rh, 3 w-tiles rw
    #pragma unroll
    for (int ks = 0; ks < 8; ++ks) {
        int kk = ks * 32 + lg * 8;
        bf16x8 bhf = ldg8(qt_hi + (bN + m) * CC + kk);
        bf16x8 blf = ldg8(qt_lo + (bN + m) * CC + kk);
        #pragma unroll
        for (int t = 0; t < 3; ++t) {
            int rowH = t * 16 + lr;
            bf16x8 ahh = ldg8(relhT_hi + rowH * CC + kk);
            bf16x8 ahl = ldg8(relhT_lo + rowH * CC + kk);
            acc[t] = MFMA(ahh, bhf, acc[t]);
            acc[t] = MFMA(ahl, bhf, acc[t]);
            acc[t] = MFMA(ahh, blf, acc[t]);
            bf16x8 awh = ldg8(relwT_hi + rowH * CC + kk);
            bf16x8 awl = ldg8(relwT_lo + rowH * CC + kk);
            acc[3 + t] = MFMA(awh, bhf, acc[3 + t]);
            acc[3 + t] = MFMA(awl, bhf, acc[3 + t]);
            acc[3 + t] = MFMA(awh, blf, acc[3 + t]);
        }
    }
    #pragma unroll
    for (int t = 0; t < 3; ++t) {
        #pragma unroll
        for (int r = 0; r < 4; ++r) {
            int h = t * 16 + lg * 4 + r;
            rhq[((size_t)b * HH + h) * NN + m] = acc[t][r];
            rwq[((size_t)b * HH + h) * NN + m] = acc[3 + t][r];
        }
    }
}

// ---- flash attention: 1 block = 144 rows (9 waves x 16), m-tiles of 64 ----
// 256 blocks exactly (16/batch x 16), 1 block/CU — balanced. Q in registers;
// K and V staged in LDS (gload_lds, XOR swizzle both sides) by waves 0-7;
// 4 K-phases/m-tile (dbuf); V [256][64] staged in quarters; PV fully LDS.
__global__ __launch_bounds__(576, 1) void k_attn(
        const __hip_bfloat16* __restrict__ qt_hi, const __hip_bfloat16* __restrict__ qt_lo,
        const __hip_bfloat16* __restrict__ kt_hi, const __hip_bfloat16* __restrict__ kt_lo,
        const float* __restrict__ rhq, const float* __restrict__ rwq,
        const __hip_bfloat16* __restrict__ vbuf, float* __restrict__ out) {
    __shared__ __align__(16) __hip_bfloat16 lds_k[2][2][64][64];  // [buf][plane][row][k] 32KB
    __shared__ __align__(16) __hip_bfloat16 lds_v[256][64];       // [c][m] 32KB (swizzled)
    __shared__ __align__(16) __hip_bfloat16 lds_p[9][16][64];     // per-wave P tile 18KB (swizzled)
    int bid = blockIdx.x;
    int b = bid >> 4;                 // 16 blocks per batch
    int n0 = (bid & 15) * 144;        // 144 rows per block
    int wave = threadIdx.x >> 6, lane = threadIdx.x & 63;
    int lr = lane & 15, lg = lane >> 4;
    int rowA = n0 + wave * 16 + lr;
    const size_t bN = (size_t)b * NN;

    // Q fragments in registers: 16 rows x 256 k per wave, hi+lo
    bf16x8 qh[8], ql[8];
    #pragma unroll
    for (int ks = 0; ks < 8; ++ks) {
        int kk = ks * 32 + lg * 8;
        qh[ks] = ldg8(qt_hi + (bN + rowA) * CC + kk);
        ql[ks] = ldg8(qt_lo + (bN + rowA) * CC + kk);
    }
    // pos-table row indices for this lane's 4 output rows
    int hn[4], wn[4];
    #pragma unroll
    for (int r = 0; r < 4; ++r) {
        int n = n0 + wave * 16 + lg * 4 + r;
        hn[r] = n % HH;
        wn[r] = n / HH;
    }
    const float* rhq_b = rhq + (size_t)b * HH * NN;
    const float* rwq_b = rwq + (size_t)b * HH * NN;

    f32x4 oacc[16] = {};
    float mrun[4] = {-1e30f, -1e30f, -1e30f, -1e30f};
    float lrun[4] = {0.f, 0.f, 0.f, 0.f};

    // staging (waves 0-7 only): LDS dest linear (lane*16B); global source chunk
    // pre-swizzled so logical chunk c of row r lands at physical chunk c^(r&7).
    int srl = lane >> 3;                      // row within wave's 8-row group
    int sch = ((lane & 7) ^ srl) * 8;         // pre-swizzled source k-offset (elems)
    auto STAGE_K = [&](int buf, int m0s, int k0) {
        if (wave >= 8) return;
        int grow = m0s + wave * 8 + srl;
        const __hip_bfloat16* sH = kt_hi + (bN + grow) * CC + k0 + sch;
        const __hip_bfloat16* sL = kt_lo + (bN + grow) * CC + k0 + sch;
        gload_lds16(sH, &lds_k[buf][0][wave * 8][0]);
        gload_lds16(sL, &lds_k[buf][1][wave * 8][0]);
    };
    auto STAGE_V = [&](int q, int m0s) {       // quarter q: c-rows [q*64, q*64+64)
        if (wave >= 8) return;
        int crow = q * 64 + wave * 8 + srl;
        const __hip_bfloat16* sV = vbuf + ((size_t)b * CC + crow) * NN + m0s + sch;
        gload_lds16(sV, &lds_v[q * 64 + wave * 8][0]);
    };

    int cur = 0;
    STAGE_K(0, 0, 0);
    __syncthreads();

    for (int t = 0; t < 36; ++t) {
        int m0 = t * 64;
        // pos adds (issued at tile start; consumed after 4 phases — hidden)
        float padd[4][4];
        #pragma unroll
        for (int mt = 0; mt < 4; ++mt) {
            int m = m0 + mt * 16 + lr;
            #pragma unroll
            for (int r = 0; r < 4; ++r)
                padd[mt][r] = rhq_b[(size_t)hn[r] * NN + m] + rwq_b[(size_t)wn[r] * NN + m];
        }
        // ---- S tile [16n x 64m], K=256 in 4 phases of 64, 3-pass split ----
        f32x4 sacc[4] = {};
        #pragma unroll
        for (int ph = 0; ph < 4; ++ph) {
            int nk = (ph + 1) * 64;
            if (nk < 256) STAGE_K(cur ^ 1, m0, nk);
            else if (t + 1 < 36) STAGE_K(cur ^ 1, m0 + 64, 0);
            STAGE_V(ph, m0);                       // quarter ph of current tile
            #pragma unroll
            for (int ks = 0; ks < 2; ++ks) {
                #pragma unroll
                for (int mt = 0; mt < 4; ++mt) {
                    int row = mt * 16 + lr;
                    int ch = ((ks * 4 + lg) ^ (lr & 7)) * 8;   // swizzled read
                    bf16x8 bh = *reinterpret_cast<const bf16x8*>(&lds_k[cur][0][row][ch]);
                    bf16x8 bl = *reinterpret_cast<const bf16x8*>(&lds_k[cur][1][row][ch]);
                    sacc[mt] = MFMA(qh[ph * 2 + ks], bh, sacc[mt]);
                    sacc[mt] = MFMA(qh[ph * 2 + ks], bl, sacc[mt]);
                    sacc[mt] = MFMA(ql[ph * 2 + ks], bh, sacc[mt]);
                }
            }
            __syncthreads();
            cur ^= 1;
        }
        // ---- add pos term, online softmax ----
        #pragma unroll
        for (int mt = 0; mt < 4; ++mt)
            #pragma unroll
            for (int r = 0; r < 4; ++r)
                sacc[mt][r] += padd[mt][r];
        #pragma unroll
        for (int r = 0; r < 4; ++r) {
            float smax = fmaxf(fmaxf(sacc[0][r], sacc[1][r]), fmaxf(sacc[2][r], sacc[3][r]));
            #pragma unroll
            for (int mk = 1; mk <= 8; mk <<= 1)
                smax = fmaxf(smax, __shfl_xor(smax, mk));
            float mnew = fmaxf(mrun[r], smax);
            float scale = __expf(mrun[r] - mnew);
            float rsum = 0.f;
            #pragma unroll
            for (int mt = 0; mt < 4; ++mt) {
                float p = __expf(sacc[mt][r] - mnew);
                sacc[mt][r] = p;
                rsum += p;
            }
            #pragma unroll
            for (int mk = 1; mk <= 8; mk <<= 1)
                rsum += __shfl_xor(rsum, mk);
            lrun[r] = lrun[r] * scale + rsum;
            mrun[r] = mnew;
            #pragma unroll
            for (int ct = 0; ct < 16; ++ct) oacc[ct][r] *= scale;
        }
        // ---- P -> LDS (transpose for PV A-frags), wave-private, XOR-swizzled
        #pragma unroll
        for (int mt = 0; mt < 4; ++mt) {
            #pragma unroll
            for (int r = 0; r < 4; ++r) {
                int prow = lg * 4 + r;
                int pcol = mt * 16 + lr;
                int pcol_s = (((pcol >> 3) ^ (prow & 7)) << 3) | (pcol & 7);
                lds_p[wave][prow][pcol_s] = __float2bfloat16(sacc[mt][r]);
            }
        }
        // ---- PV from LDS: out_t[n][c] += sum_m P[n][m] * v[c][m] ----
        #pragma unroll
        for (int ks2 = 0; ks2 < 2; ++ks2) {
            int pch = ((ks2 * 4 + lg) ^ (lr & 7)) * 8;         // swizzled read
            bf16x8 pa = *reinterpret_cast<const bf16x8*>(&lds_p[wave][lr][pch]);
            #pragma unroll
            for (int ct = 0; ct < 16; ++ct) {
                int vrow = ct * 16 + lr;
                bf16x8 bvv = *reinterpret_cast<const bf16x8*>(&lds_v[vrow][pch]);
                oacc[ct] = MFMA(pa, bvv, oacc[ct]);
            }
        }
        __syncthreads();   // protect lds_v (read) from next tile's restage (write)
    }
    // ---- epilogue: normalize and store out[b][c][n] ----
    #pragma unroll
    for (int ct = 0; ct < 16; ++ct) {
        int c = ct * 16 + lr;
        #pragma unroll
        for (int r = 0; r < 4; ++r) {
            int n = n0 + wave * 16 + lg * 4 + r;
            out[((size_t)b * CC + c) * NN + n] = oacc[ct][r] / lrun[r];
        }
    }
}

extern "C" void kernel_launch(void* const* d_in, const int* in_sizes, int n_in,
                              void* d_out, int out_size, void* d_ws, size_t ws_size,
                              hipStream_t stream) {
    const float* x     = (const float*)d_in[0];
    const float* Wq    = (const float*)d_in[1];
    const float* bq    = (const float*)d_in[2];
    const float* Wk    = (const float*)d_in[3];
    const float* bk    = (const float*)d_in[4];
    const float* Wv    = (const float*)d_in[5];
    const float* bv    = (const float*)d_in[6];
    const float* rel_h = (const float*)d_in[7];
    const float* rel_w = (const float*)d_in[8];
    float* out = (float*)d_out;

    size_t off = 0;
    auto carve = [&](size_t bytes) {
        void* p = (char*)d_ws + off;
        off += (bytes + 255) & ~(size_t)255;
        return p;
    };
    const size_t sz_t = (size_t)BB * NN * CC * sizeof(__hip_bfloat16);
    __hip_bfloat16* xt_hi  = (__hip_bfloat16*)carve(sz_t);
    __hip_bfloat16* xt_lo  = (__hip_bfloat16*)carve(sz_t);
    __hip_bfloat16* qt_hi  = (__hip_bfloat16*)carve(sz_t);
    __hip_bfloat16* qt_lo  = (__hip_bfloat16*)carve(sz_t);
    __hip_bfloat16* kt_hi  = (__hip_bfloat16*)carve(sz_t);
    __hip_bfloat16* kt_lo  = (__hip_bfloat16*)carve(sz_t);
    __hip_bfloat16* vbuf   = (__hip_bfloat16*)carve(sz_t);
    __hip_bfloat16* relhT_hi = (__hip_bfloat16*)carve((size_t)HH * CC * 2);
    __hip_bfloat16* relhT_lo = (__hip_bfloat16*)carve((size_t)HH * CC * 2);
    __hip_bfloat16* relwT_hi = (__hip_bfloat16*)carve((size_t)HH * CC * 2);
    __hip_bfloat16* relwT_lo = (__hip_bfloat16*)carve((size_t)HH * CC * 2);
    __hip_bfloat16* w_hi   = (__hip_bfloat16*)carve((size_t)3 * CC * CC * 2);
    __hip_bfloat16* w_lo   = (__hip_bfloat16*)carve((size_t)3 * CC * CC * 2);
    float* rhq = (float*)carve((size_t)BB * HH * NN * 4);
    float* rwq = (float*)carve((size_t)BB * HH * NN * 4);
    if (off > ws_size) return;   // workspace too small -> output stays poisoned (visible failure)

    k_prep_x<<<dim3(NN / 64, CC / 64, BB), 256, 0, stream>>>(x, xt_hi, xt_lo);
    k_prep_w<<<dim3(3 * CC * CC / 256), 256, 0, stream>>>(Wq, Wk, Wv, w_hi, w_lo);
    k_prep_rel<<<dim3(HH * CC / 256), 256, 0, stream>>>(rel_h, rel_w,
        relhT_hi, relhT_lo, relwT_hi, relwT_lo);
    k_proj<<<dim3((NN / 64) * (CC / 64), BB, 3), 256, 0, stream>>>(
        xt_hi, xt_lo, w_hi, w_lo, bq, bk, bv, qt_hi, qt_lo, kt_hi, kt_lo, vbuf);
    k_posq<<<dim3(NN / 64, BB), 256, 0, stream>>>(
        qt_hi, qt_lo, relhT_hi, relhT_lo, relwT_hi, relwT_lo, rhq, rwq);
    k_attn<<<dim3(256), 576, 0, stream>>>(
        qt_hi, qt_lo, kt_hi, kt_lo, rhq, rwq, vbuf, out);
}

// Round 8
// 912.406 us; speedup vs baseline: 1.0247x; 1.0247x over previous
//
#include <hip/hip_runtime.h>
#include <hip/hip_bf16.h>

// MHSA: B=16, C=256, H=W=48, N=2304.
// S[b,n,m] = q[b,:,n]·k[b,:,m] + rhq[b][n%48][m] + rwq[b][n/48][m]
//   rhq = rel_h^T q, rwq = rel_w^T q  (rank-split of the pos term, fp32)
// att = softmax_m(S); out[b,c,n] = sum_m v[b,c,m] att[n,m]
// fp32 accuracy for logits via split-bf16 (hi+lo, 3 MFMA passes).
//
// R7 lesson: 256 blocks with 16/batch aligned to 8 XCDs (16%8==0) put 2 blocks
// of EVERY batch on EVERY XCD -> 16 streams per 4MB L2 -> thrash (FETCH 1.09GB,
// HBM-bound 646us). R8: explicit batch->XCD grouping swizzle: batch b's 16
// blocks share one XCD (2 batches/XCD, 32 co-resident lockstep blocks); reuse
// window ~300KB << 4MB. Balance (1 blk/CU) retained from R7.

#define BB 16
#define CC 256
#define HH 48
#define NN 2304

typedef float f32x4 __attribute__((ext_vector_type(4)));
typedef short bf16x8 __attribute__((ext_vector_type(8)));

#define MFMA(a, b, c) __builtin_amdgcn_mfma_f32_16x16x32_bf16((a), (b), (c), 0, 0, 0)

__device__ inline bf16x8 ldg8(const __hip_bfloat16* p) {
    return *reinterpret_cast<const bf16x8*>(p);
}

typedef __attribute__((address_space(3))) unsigned int lds_uint;
typedef const __attribute__((address_space(1))) unsigned int gbl_uint;

__device__ inline void gload_lds16(const __hip_bfloat16* g, __hip_bfloat16* l) {
    __builtin_amdgcn_global_load_lds((gbl_uint*)g, (lds_uint*)l, 16, 0, 0);
}

// ---- prep: transpose x [b][c][n] -> xT [b][n][c], split into bf16 hi/lo ----
__global__ __launch_bounds__(256) void k_prep_x(const float* __restrict__ x,
        __hip_bfloat16* __restrict__ xt_hi, __hip_bfloat16* __restrict__ xt_lo) {
    __shared__ float tile[64][65];
    int b = blockIdx.z, n0 = blockIdx.x * 64, c0 = blockIdx.y * 64;
    const float* xb = x + (size_t)b * CC * NN;
    #pragma unroll
    for (int i = 0; i < 16; ++i) {
        int idx = i * 256 + threadIdx.x;
        int r = idx >> 6, col = idx & 63;
        tile[r][col] = xb[(size_t)(c0 + r) * NN + n0 + col];
    }
    __syncthreads();
    #pragma unroll
    for (int i = 0; i < 16; ++i) {
        int idx = i * 256 + threadIdx.x;
        int r = idx >> 6, col = idx & 63;           // r = n-local, col = c-local
        float v = tile[col][r];
        __hip_bfloat16 h = __float2bfloat16(v);
        size_t o = ((size_t)b * NN + n0 + r) * CC + c0 + col;
        xt_hi[o] = h;
        xt_lo[o] = __float2bfloat16(v - __bfloat162float(h));
    }
}

// ---- prep: split Wq/Wk/Wv into hi/lo (layout [3][256][256] row-major) ----
__global__ __launch_bounds__(256) void k_prep_w(const float* __restrict__ Wq,
        const float* __restrict__ Wk, const float* __restrict__ Wv,
        __hip_bfloat16* __restrict__ w_hi, __hip_bfloat16* __restrict__ w_lo) {
    int i = blockIdx.x * 256 + threadIdx.x;         // < 3*65536
    int m = i >> 16, j = i & 65535;
    const float* W = (m == 0) ? Wq : ((m == 1) ? Wk : Wv);
    float v = W[j];
    __hip_bfloat16 h = __float2bfloat16(v);
    w_hi[i] = h;
    w_lo[i] = __float2bfloat16(v - __bfloat162float(h));
}

// ---- prep: relhT[h][c] = rel_h[c][h], relwT[w][c] = rel_w[c][w], hi/lo split
__global__ __launch_bounds__(256) void k_prep_rel(const float* __restrict__ rel_h,
        const float* __restrict__ rel_w,
        __hip_bfloat16* __restrict__ relhT_hi, __hip_bfloat16* __restrict__ relhT_lo,
        __hip_bfloat16* __restrict__ relwT_hi, __hip_bfloat16* __restrict__ relwT_lo) {
    int i = blockIdx.x * 256 + threadIdx.x;         // < 48*256
    int h = i >> 8, c = i & 255;
    float vh = rel_h[c * HH + h];
    float vw = rel_w[c * HH + h];
    __hip_bfloat16 hh = __float2bfloat16(vh);
    relhT_hi[i] = hh;
    relhT_lo[i] = __float2bfloat16(vh - __bfloat162float(hh));
    __hip_bfloat16 hw = __float2bfloat16(vw);
    relwT_hi[i] = hw;
    relwT_lo[i] = __float2bfloat16(vw - __bfloat162float(hw));
}

// ---- projection GEMM: yT[b][n][o] = sum_c xT[b][n][c] * W[o][c] + bias[o] ----
// pj=0 -> qT hi/lo, pj=1 -> kT hi/lo, pj=2 -> v[b][o][n] bf16
__global__ __launch_bounds__(256) void k_proj(
        const __hip_bfloat16* __restrict__ xt_hi, const __hip_bfloat16* __restrict__ xt_lo,
        const __hip_bfloat16* __restrict__ w_hi,  const __hip_bfloat16* __restrict__ w_lo,
        const float* __restrict__ bq, const float* __restrict__ bk, const float* __restrict__ bv,
        __hip_bfloat16* __restrict__ qt_hi, __hip_bfloat16* __restrict__ qt_lo,
        __hip_bfloat16* __restrict__ kt_hi, __hip_bfloat16* __restrict__ kt_lo,
        __hip_bfloat16* __restrict__ vbuf) {
    int b = blockIdx.y, pj = blockIdx.z;
    int n0 = (blockIdx.x >> 2) * 64, o0 = (blockIdx.x & 3) * 64;
    int wave = threadIdx.x >> 6, lane = threadIdx.x & 63;
    int lr = lane & 15, lg = lane >> 4;
    int rowA = n0 + wave * 16 + lr;
    const __hip_bfloat16* wh = w_hi + (size_t)pj * 65536;
    const __hip_bfloat16* wl = w_lo + (size_t)pj * 65536;
    const __hip_bfloat16* axh = xt_hi + ((size_t)b * NN + rowA) * CC;
    const __hip_bfloat16* axl = xt_lo + ((size_t)b * NN + rowA) * CC;
    f32x4 acc[4] = {};
    #pragma unroll
    for (int ks = 0; ks < 8; ++ks) {
        int kk = ks * 32 + lg * 8;
        bf16x8 ah = ldg8(axh + kk);
        bf16x8 al = ldg8(axl + kk);
        #pragma unroll
        for (int ot = 0; ot < 4; ++ot) {
            int rowB = o0 + ot * 16 + lr;
            bf16x8 bh = ldg8(wh + rowB * CC + kk);
            bf16x8 bl = ldg8(wl + rowB * CC + kk);
            acc[ot] = MFMA(ah, bh, acc[ot]);
            acc[ot] = MFMA(ah, bl, acc[ot]);
            acc[ot] = MFMA(al, bh, acc[ot]);
        }
    }
    const float* bias = (pj == 0) ? bq : ((pj == 1) ? bk : bv);
    #pragma unroll
    for (int ot = 0; ot < 4; ++ot) {
        int o = o0 + ot * 16 + lr;
        float bb = bias[o];
        #pragma unroll
        for (int r = 0; r < 4; ++r) {
            int n = n0 + wave * 16 + lg * 4 + r;
            float y = acc[ot][r] + bb;
            if (pj == 0) {
                __hip_bfloat16 h = __float2bfloat16(y);
                size_t off = ((size_t)b * NN + n) * CC + o;
                qt_hi[off] = h;
                qt_lo[off] = __float2bfloat16(y - __bfloat162float(h));
            } else if (pj == 1) {
                __hip_bfloat16 h = __float2bfloat16(y);
                size_t off = ((size_t)b * NN + n) * CC + o;
                kt_hi[off] = h;
                kt_lo[off] = __float2bfloat16(y - __bfloat162float(h));
            } else {
                vbuf[((size_t)b * CC + o) * NN + n] = __float2bfloat16(y);
            }
        }
    }
}

// ---- pos rank-split: rhq[b][h][m] = sum_c relhT[h][c] q[b][c][m]; same for rwq
__global__ __launch_bounds__(256) void k_posq(
        const __hip_bfloat16* __restrict__ qt_hi, const __hip_bfloat16* __restrict__ qt_lo,
        const __hip_bfloat16* __restrict__ relhT_hi, const __hip_bfloat16* __restrict__ relhT_lo,
        const __hip_bfloat16* __restrict__ relwT_hi, const __hip_bfloat16* __restrict__ relwT_lo,
        float* __restrict__ rhq, float* __restrict__ rwq) {
    int b = blockIdx.y, m0 = blockIdx.x * 64;
    int wave = threadIdx.x >> 6, lane = threadIdx.x & 63;
    int lr = lane & 15, lg = lane >> 4;
    int m = m0 + wave * 16 + lr;                    // output column
    const size_t bN = (size_t)b * NN;
    f32x4 acc[6] = {};                              // 3 h-tiles rh, 3 w-tiles rw
    #pragma unroll
    for (int ks = 0; ks < 8; ++ks) {
        int kk = ks * 32 + lg * 8;
        bf16x8 bhf = ldg8(qt_hi + (bN + m) * CC + kk);
        bf16x8 blf = ldg8(qt_lo + (bN + m) * CC + kk);
        #pragma unroll
        for (int t = 0; t < 3; ++t) {
            int rowH = t * 16 + lr;
            bf16x8 ahh = ldg8(relhT_hi + rowH * CC + kk);
            bf16x8 ahl = ldg8(relhT_lo + rowH * CC + kk);
            acc[t] = MFMA(ahh, bhf, acc[t]);
            acc[t] = MFMA(ahl, bhf, acc[t]);
            acc[t] = MFMA(ahh, blf, acc[t]);
            bf16x8 awh = ldg8(relwT_hi + rowH * CC + kk);
            bf16x8 awl = ldg8(relwT_lo + rowH * CC + kk);
            acc[3 + t] = MFMA(awh, bhf, acc[3 + t]);
            acc[3 + t] = MFMA(awl, bhf, acc[3 + t]);
            acc[3 + t] = MFMA(awh, blf, acc[3 + t]);
        }
    }
    #pragma unroll
    for (int t = 0; t < 3; ++t) {
        #pragma unroll
        for (int r = 0; r < 4; ++r) {
            int h = t * 16 + lg * 4 + r;
            rhq[((size_t)b * HH + h) * NN + m] = acc[t][r];
            rwq[((size_t)b * HH + h) * NN + m] = acc[3 + t][r];
        }
    }
}

// ---- flash attention: 1 block = 144 rows (9 waves x 16), m-tiles of 64 ----
// 256 blocks (16/batch), 1 block/CU. Batch->XCD grouping swizzle: under
// XCD=bid%8, batch b's 16 blocks share XCD b%8 (2 batches/XCD, 32 lockstep
// blocks) -> K/V stream reuse window ~300KB << 4MB L2. Q in registers; K and V
// staged in LDS (gload_lds, XOR swizzle both sides) by waves 0-7; PV fully LDS.
__global__ __launch_bounds__(576, 1) void k_attn(
        const __hip_bfloat16* __restrict__ qt_hi, const __hip_bfloat16* __restrict__ qt_lo,
        const __hip_bfloat16* __restrict__ kt_hi, const __hip_bfloat16* __restrict__ kt_lo,
        const float* __restrict__ rhq, const float* __restrict__ rwq,
        const __hip_bfloat16* __restrict__ vbuf, float* __restrict__ out) {
    __shared__ __align__(16) __hip_bfloat16 lds_k[2][2][64][64];  // [buf][plane][row][k] 32KB
    __shared__ __align__(16) __hip_bfloat16 lds_v[256][64];       // [c][m] 32KB (swizzled)
    __shared__ __align__(16) __hip_bfloat16 lds_p[9][16][64];     // per-wave P tile 18KB (swizzled)
    // batch->XCD grouping: bid = 8*s + q; b = q + 8*(s>>4); j = s&15
    int bid = blockIdx.x;
    int q_ = bid & 7, s_ = bid >> 3;
    int b = q_ + ((s_ >> 4) << 3);
    int n0 = (s_ & 15) * 144;
    int wave = threadIdx.x >> 6, lane = threadIdx.x & 63;
    int lr = lane & 15, lg = lane >> 4;
    int rowA = n0 + wave * 16 + lr;
    const size_t bN = (size_t)b * NN;

    // Q fragments in registers: 16 rows x 256 k per wave, hi+lo
    bf16x8 qh[8], ql[8];
    #pragma unroll
    for (int ks = 0; ks < 8; ++ks) {
        int kk = ks * 32 + lg * 8;
        qh[ks] = ldg8(qt_hi + (bN + rowA) * CC + kk);
        ql[ks] = ldg8(qt_lo + (bN + rowA) * CC + kk);
    }
    // pos-table row indices for this lane's 4 output rows
    int hn[4], wn[4];
    #pragma unroll
    for (int r = 0; r < 4; ++r) {
        int n = n0 + wave * 16 + lg * 4 + r;
        hn[r] = n % HH;
        wn[r] = n / HH;
    }
    const float* rhq_b = rhq + (size_t)b * HH * NN;
    const float* rwq_b = rwq + (size_t)b * HH * NN;

    f32x4 oacc[16] = {};
    float mrun[4] = {-1e30f, -1e30f, -1e30f, -1e30f};
    float lrun[4] = {0.f, 0.f, 0.f, 0.f};

    // staging (waves 0-7 only): LDS dest linear (lane*16B); global source chunk
    // pre-swizzled so logical chunk c of row r lands at physical chunk c^(r&7).
    int srl = lane >> 3;                      // row within wave's 8-row group
    int sch = ((lane & 7) ^ srl) * 8;         // pre-swizzled source k-offset (elems)
    auto STAGE_K = [&](int buf, int m0s, int k0) {
        if (wave >= 8) return;
        int grow = m0s + wave * 8 + srl;
        const __hip_bfloat16* sH = kt_hi + (bN + grow) * CC + k0 + sch;
        const __hip_bfloat16* sL = kt_lo + (bN + grow) * CC + k0 + sch;
        gload_lds16(sH, &lds_k[buf][0][wave * 8][0]);
        gload_lds16(sL, &lds_k[buf][1][wave * 8][0]);
    };
    auto STAGE_V = [&](int q, int m0s) {       // quarter q: c-rows [q*64, q*64+64)
        if (wave >= 8) return;
        int crow = q * 64 + wave * 8 + srl;
        const __hip_bfloat16* sV = vbuf + ((size_t)b * CC + crow) * NN + m0s + sch;
        gload_lds16(sV, &lds_v[q * 64 + wave * 8][0]);
    };

    int cur = 0;
    STAGE_K(0, 0, 0);
    __syncthreads();

    for (int t = 0; t < 36; ++t) {
        int m0 = t * 64;
        // pos adds (issued at tile start; consumed after 4 phases — hidden)
        float padd[4][4];
        #pragma unroll
        for (int mt = 0; mt < 4; ++mt) {
            int m = m0 + mt * 16 + lr;
            #pragma unroll
            for (int r = 0; r < 4; ++r)
                padd[mt][r] = rhq_b[(size_t)hn[r] * NN + m] + rwq_b[(size_t)wn[r] * NN + m];
        }
        // ---- S tile [16n x 64m], K=256 in 4 phases of 64, 3-pass split ----
        f32x4 sacc[4] = {};
        #pragma unroll
        for (int ph = 0; ph < 4; ++ph) {
            int nk = (ph + 1) * 64;
            if (nk < 256) STAGE_K(cur ^ 1, m0, nk);
            else if (t + 1 < 36) STAGE_K(cur ^ 1, m0 + 64, 0);
            STAGE_V(ph, m0);                       // quarter ph of current tile
            #pragma unroll
            for (int ks = 0; ks < 2; ++ks) {
                #pragma unroll
                for (int mt = 0; mt < 4; ++mt) {
                    int row = mt * 16 + lr;
                    int ch = ((ks * 4 + lg) ^ (lr & 7)) * 8;   // swizzled read
                    bf16x8 bh = *reinterpret_cast<const bf16x8*>(&lds_k[cur][0][row][ch]);
                    bf16x8 bl = *reinterpret_cast<const bf16x8*>(&lds_k[cur][1][row][ch]);
                    sacc[mt] = MFMA(qh[ph * 2 + ks], bh, sacc[mt]);
                    sacc[mt] = MFMA(qh[ph * 2 + ks], bl, sacc[mt]);
                    sacc[mt] = MFMA(ql[ph * 2 + ks], bh, sacc[mt]);
                }
            }
            __syncthreads();
            cur ^= 1;
        }
        // ---- add pos term, online softmax ----
        #pragma unroll
        for (int mt = 0; mt < 4; ++mt)
            #pragma unroll
            for (int r = 0; r < 4; ++r)
                sacc[mt][r] += padd[mt][r];
        #pragma unroll
        for (int r = 0; r < 4; ++r) {
            float smax = fmaxf(fmaxf(sacc[0][r], sacc[1][r]), fmaxf(sacc[2][r], sacc[3][r]));
            #pragma unroll
            for (int mk = 1; mk <= 8; mk <<= 1)
                smax = fmaxf(smax, __shfl_xor(smax, mk));
            float mnew = fmaxf(mrun[r], smax);
            float scale = __expf(mrun[r] - mnew);
            float rsum = 0.f;
            #pragma unroll
            for (int mt = 0; mt < 4; ++mt) {
                float p = __expf(sacc[mt][r] - mnew);
                sacc[mt][r] = p;
                rsum += p;
            }
            #pragma unroll
            for (int mk = 1; mk <= 8; mk <<= 1)
                rsum += __shfl_xor(rsum, mk);
            lrun[r] = lrun[r] * scale + rsum;
            mrun[r] = mnew;
            #pragma unroll
            for (int ct = 0; ct < 16; ++ct) oacc[ct][r] *= scale;
        }
        // ---- P -> LDS (transpose for PV A-frags), wave-private, XOR-swizzled
        #pragma unroll
        for (int mt = 0; mt < 4; ++mt) {
            #pragma unroll
            for (int r = 0; r < 4; ++r) {
                int prow = lg * 4 + r;
                int pcol = mt * 16 + lr;
                int pcol_s = (((pcol >> 3) ^ (prow & 7)) << 3) | (pcol & 7);
                lds_p[wave][prow][pcol_s] = __float2bfloat16(sacc[mt][r]);
            }
        }
        // ---- PV from LDS: out_t[n][c] += sum_m P[n][m] * v[c][m] ----
        #pragma unroll
        for (int ks2 = 0; ks2 < 2; ++ks2) {
            int pch = ((ks2 * 4 + lg) ^ (lr & 7)) * 8;         // swizzled read
            bf16x8 pa = *reinterpret_cast<const bf16x8*>(&lds_p[wave][lr][pch]);
            #pragma unroll
            for (int ct = 0; ct < 16; ++ct) {
                int vrow = ct * 16 + lr;
                bf16x8 bvv = *reinterpret_cast<const bf16x8*>(&lds_v[vrow][pch]);
                oacc[ct] = MFMA(pa, bvv, oacc[ct]);
            }
        }
        __syncthreads();   // protect lds_v (read) from next tile's restage (write)
    }
    // ---- epilogue: normalize and store out[b][c][n] ----
    #pragma unroll
    for (int ct = 0; ct < 16; ++ct) {
        int c = ct * 16 + lr;
        #pragma unroll
        for (int r = 0; r < 4; ++r) {
            int n = n0 + wave * 16 + lg * 4 + r;
            out[((size_t)b * CC + c) * NN + n] = oacc[ct][r] / lrun[r];
        }
    }
}

extern "C" void kernel_launch(void* const* d_in, const int* in_sizes, int n_in,
                              void* d_out, int out_size, void* d_ws, size_t ws_size,
                              hipStream_t stream) {
    const float* x     = (const float*)d_in[0];
    const float* Wq    = (const float*)d_in[1];
    const float* bq    = (const float*)d_in[2];
    const float* Wk    = (const float*)d_in[3];
    const float* bk    = (const float*)d_in[4];
    const float* Wv    = (const float*)d_in[5];
    const float* bv    = (const float*)d_in[6];
    const float* rel_h = (const float*)d_in[7];
    const float* rel_w = (const float*)d_in[8];
    float* out = (float*)d_out;

    size_t off = 0;
    auto carve = [&](size_t bytes) {
        void* p = (char*)d_ws + off;
        off += (bytes + 255) & ~(size_t)255;
        return p;
    };
    const size_t sz_t = (size_t)BB * NN * CC * sizeof(__hip_bfloat16);
    __hip_bfloat16* xt_hi  = (__hip_bfloat16*)carve(sz_t);
    __hip_bfloat16* xt_lo  = (__hip_bfloat16*)carve(sz_t);
    __hip_bfloat16* qt_hi  = (__hip_bfloat16*)carve(sz_t);
    __hip_bfloat16* qt_lo  = (__hip_bfloat16*)carve(sz_t);
    __hip_bfloat16* kt_hi  = (__hip_bfloat16*)carve(sz_t);
    __hip_bfloat16* kt_lo  = (__hip_bfloat16*)carve(sz_t);
    __hip_bfloat16* vbuf   = (__hip_bfloat16*)carve(sz_t);
    __hip_bfloat16* relhT_hi = (__hip_bfloat16*)carve((size_t)HH * CC * 2);
    __hip_bfloat16* relhT_lo = (__hip_bfloat16*)carve((size_t)HH * CC * 2);
    __hip_bfloat16* relwT_hi = (__hip_bfloat16*)carve((size_t)HH * CC * 2);
    __hip_bfloat16* relwT_lo = (__hip_bfloat16*)carve((size_t)HH * CC * 2);
    __hip_bfloat16* w_hi   = (__hip_bfloat16*)carve((size_t)3 * CC * CC * 2);
    __hip_bfloat16* w_lo   = (__hip_bfloat16*)carve((size_t)3 * CC * CC * 2);
    float* rhq = (float*)carve((size_t)BB * HH * NN * 4);
    float* rwq = (float*)carve((size_t)BB * HH * NN * 4);
    if (off > ws_size) return;   // workspace too small -> output stays poisoned (visible failure)

    k_prep_x<<<dim3(NN / 64, CC / 64, BB), 256, 0, stream>>>(x, xt_hi, xt_lo);
    k_prep_w<<<dim3(3 * CC * CC / 256), 256, 0, stream>>>(Wq, Wk, Wv, w_hi, w_lo);
    k_prep_rel<<<dim3(HH * CC / 256), 256, 0, stream>>>(rel_h, rel_w,
        relhT_hi, relhT_lo, relwT_hi, relwT_lo);
    k_proj<<<dim3((NN / 64) * (CC / 64), BB, 3), 256, 0, stream>>>(
        xt_hi, xt_lo, w_hi, w_lo, bq, bk, bv, qt_hi, qt_lo, kt_hi, kt_lo, vbuf);
    k_posq<<<dim3(NN / 64, BB), 256, 0, stream>>>(
        qt_hi, qt_lo, relhT_hi, relhT_lo, relwT_hi, relwT_lo, rhq, rwq);
    k_attn<<<dim3(256), 576, 0, stream>>>(
        qt_hi, qt_lo, kt_hi, kt_lo, rhq, rwq, vbuf, out);
}

// Round 9
// 903.448 us; speedup vs baseline: 1.0348x; 1.0099x over previous
//
#include <hip/hip_runtime.h>
#include <hip/hip_bf16.h>

// MHSA: B=16, C=256, H=W=48, N=2304.
// S[b,n,m] = q[b,:,n]·k[b,:,m] + rhq[b][n%48][m] + rwq[b][n/48][m]
//   rhq = rel_h^T q, rwq = rel_w^T q  (rank-split of the pos term, fp32)
// att = softmax_m(S); out[b,c,n] = sum_m v[b,c,m] att[n,m]
// fp32 accuracy for logits via split-bf16 (hi+lo, 3 MFMA passes).
//
// R9: revert to the R6 grid (288 blocks x 8 waves x 128 rows — best measured:
// 437us, FETCH 280MB) and remove the structural stall: __syncthreads drains
// vmcnt(0) each phase, exposing full staging latency 144x per block. Replace
// with counted s_waitcnt vmcnt(3/2) + raw s_barrier (guide T3/T4): prefetch
// trio [V,Khi,Klo] stays in flight across barriers; never drain to 0 in-loop.

#define BB 16
#define CC 256
#define HH 48
#define NN 2304

typedef float f32x4 __attribute__((ext_vector_type(4)));
typedef short bf16x8 __attribute__((ext_vector_type(8)));

#define MFMA(a, b, c) __builtin_amdgcn_mfma_f32_16x16x32_bf16((a), (b), (c), 0, 0, 0)

#define BAR()    asm volatile("s_barrier" ::: "memory")
#define WAITV(N) asm volatile("s_waitcnt vmcnt(" #N ")" ::: "memory")
#define WAITL()  asm volatile("s_waitcnt lgkmcnt(0)" ::: "memory")

__device__ inline bf16x8 ldg8(const __hip_bfloat16* p) {
    return *reinterpret_cast<const bf16x8*>(p);
}

typedef __attribute__((address_space(3))) unsigned int lds_uint;
typedef const __attribute__((address_space(1))) unsigned int gbl_uint;

__device__ inline void gload_lds16(const __hip_bfloat16* g, __hip_bfloat16* l) {
    __builtin_amdgcn_global_load_lds((gbl_uint*)g, (lds_uint*)l, 16, 0, 0);
}

// ---- prep: transpose x [b][c][n] -> xT [b][n][c], split into bf16 hi/lo ----
__global__ __launch_bounds__(256) void k_prep_x(const float* __restrict__ x,
        __hip_bfloat16* __restrict__ xt_hi, __hip_bfloat16* __restrict__ xt_lo) {
    __shared__ float tile[64][65];
    int b = blockIdx.z, n0 = blockIdx.x * 64, c0 = blockIdx.y * 64;
    const float* xb = x + (size_t)b * CC * NN;
    #pragma unroll
    for (int i = 0; i < 16; ++i) {
        int idx = i * 256 + threadIdx.x;
        int r = idx >> 6, col = idx & 63;
        tile[r][col] = xb[(size_t)(c0 + r) * NN + n0 + col];
    }
    __syncthreads();
    #pragma unroll
    for (int i = 0; i < 16; ++i) {
        int idx = i * 256 + threadIdx.x;
        int r = idx >> 6, col = idx & 63;           // r = n-local, col = c-local
        float v = tile[col][r];
        __hip_bfloat16 h = __float2bfloat16(v);
        size_t o = ((size_t)b * NN + n0 + r) * CC + c0 + col;
        xt_hi[o] = h;
        xt_lo[o] = __float2bfloat16(v - __bfloat162float(h));
    }
}

// ---- prep: split Wq/Wk/Wv into hi/lo (layout [3][256][256] row-major) ----
__global__ __launch_bounds__(256) void k_prep_w(const float* __restrict__ Wq,
        const float* __restrict__ Wk, const float* __restrict__ Wv,
        __hip_bfloat16* __restrict__ w_hi, __hip_bfloat16* __restrict__ w_lo) {
    int i = blockIdx.x * 256 + threadIdx.x;         // < 3*65536
    int m = i >> 16, j = i & 65535;
    const float* W = (m == 0) ? Wq : ((m == 1) ? Wk : Wv);
    float v = W[j];
    __hip_bfloat16 h = __float2bfloat16(v);
    w_hi[i] = h;
    w_lo[i] = __float2bfloat16(v - __bfloat162float(h));
}

// ---- prep: relhT[h][c] = rel_h[c][h], relwT[w][c] = rel_w[c][w], hi/lo split
__global__ __launch_bounds__(256) void k_prep_rel(const float* __restrict__ rel_h,
        const float* __restrict__ rel_w,
        __hip_bfloat16* __restrict__ relhT_hi, __hip_bfloat16* __restrict__ relhT_lo,
        __hip_bfloat16* __restrict__ relwT_hi, __hip_bfloat16* __restrict__ relwT_lo) {
    int i = blockIdx.x * 256 + threadIdx.x;         // < 48*256
    int h = i >> 8, c = i & 255;
    float vh = rel_h[c * HH + h];
    float vw = rel_w[c * HH + h];
    __hip_bfloat16 hh = __float2bfloat16(vh);
    relhT_hi[i] = hh;
    relhT_lo[i] = __float2bfloat16(vh - __bfloat162float(hh));
    __hip_bfloat16 hw = __float2bfloat16(vw);
    relwT_hi[i] = hw;
    relwT_lo[i] = __float2bfloat16(vw - __bfloat162float(hw));
}

// ---- projection GEMM: yT[b][n][o] = sum_c xT[b][n][c] * W[o][c] + bias[o] ----
// pj=0 -> qT hi/lo, pj=1 -> kT hi/lo, pj=2 -> v[b][o][n] bf16
__global__ __launch_bounds__(256) void k_proj(
        const __hip_bfloat16* __restrict__ xt_hi, const __hip_bfloat16* __restrict__ xt_lo,
        const __hip_bfloat16* __restrict__ w_hi,  const __hip_bfloat16* __restrict__ w_lo,
        const float* __restrict__ bq, const float* __restrict__ bk, const float* __restrict__ bv,
        __hip_bfloat16* __restrict__ qt_hi, __hip_bfloat16* __restrict__ qt_lo,
        __hip_bfloat16* __restrict__ kt_hi, __hip_bfloat16* __restrict__ kt_lo,
        __hip_bfloat16* __restrict__ vbuf) {
    int b = blockIdx.y, pj = blockIdx.z;
    int n0 = (blockIdx.x >> 2) * 64, o0 = (blockIdx.x & 3) * 64;
    int wave = threadIdx.x >> 6, lane = threadIdx.x & 63;
    int lr = lane & 15, lg = lane >> 4;
    int rowA = n0 + wave * 16 + lr;
    const __hip_bfloat16* wh = w_hi + (size_t)pj * 65536;
    const __hip_bfloat16* wl = w_lo + (size_t)pj * 65536;
    const __hip_bfloat16* axh = xt_hi + ((size_t)b * NN + rowA) * CC;
    const __hip_bfloat16* axl = xt_lo + ((size_t)b * NN + rowA) * CC;
    f32x4 acc[4] = {};
    #pragma unroll
    for (int ks = 0; ks < 8; ++ks) {
        int kk = ks * 32 + lg * 8;
        bf16x8 ah = ldg8(axh + kk);
        bf16x8 al = ldg8(axl + kk);
        #pragma unroll
        for (int ot = 0; ot < 4; ++ot) {
            int rowB = o0 + ot * 16 + lr;
            bf16x8 bh = ldg8(wh + rowB * CC + kk);
            bf16x8 bl = ldg8(wl + rowB * CC + kk);
            acc[ot] = MFMA(ah, bh, acc[ot]);
            acc[ot] = MFMA(ah, bl, acc[ot]);
            acc[ot] = MFMA(al, bh, acc[ot]);
        }
    }
    const float* bias = (pj == 0) ? bq : ((pj == 1) ? bk : bv);
    #pragma unroll
    for (int ot = 0; ot < 4; ++ot) {
        int o = o0 + ot * 16 + lr;
        float bb = bias[o];
        #pragma unroll
        for (int r = 0; r < 4; ++r) {
            int n = n0 + wave * 16 + lg * 4 + r;
            float y = acc[ot][r] + bb;
            if (pj == 0) {
                __hip_bfloat16 h = __float2bfloat16(y);
                size_t off = ((size_t)b * NN + n) * CC + o;
                qt_hi[off] = h;
                qt_lo[off] = __float2bfloat16(y - __bfloat162float(h));
            } else if (pj == 1) {
                __hip_bfloat16 h = __float2bfloat16(y);
                size_t off = ((size_t)b * NN + n) * CC + o;
                kt_hi[off] = h;
                kt_lo[off] = __float2bfloat16(y - __bfloat162float(h));
            } else {
                vbuf[((size_t)b * CC + o) * NN + n] = __float2bfloat16(y);
            }
        }
    }
}

// ---- pos rank-split: rhq[b][h][m] = sum_c relhT[h][c] q[b][c][m]; same for rwq
__global__ __launch_bounds__(256) void k_posq(
        const __hip_bfloat16* __restrict__ qt_hi, const __hip_bfloat16* __restrict__ qt_lo,
        const __hip_bfloat16* __restrict__ relhT_hi, const __hip_bfloat16* __restrict__ relhT_lo,
        const __hip_bfloat16* __restrict__ relwT_hi, const __hip_bfloat16* __restrict__ relwT_lo,
        float* __restrict__ rhq, float* __restrict__ rwq) {
    int b = blockIdx.y, m0 = blockIdx.x * 64;
    int wave = threadIdx.x >> 6, lane = threadIdx.x & 63;
    int lr = lane & 15, lg = lane >> 4;
    int m = m0 + wave * 16 + lr;                    // output column
    const size_t bN = (size_t)b * NN;
    f32x4 acc[6] = {};                              // 3 h-tiles rh, 3 w-tiles rw
    #pragma unroll
    for (int ks = 0; ks < 8; ++ks) {
        int kk = ks * 32 + lg * 8;
        bf16x8 bhf = ldg8(qt_hi + (bN + m) * CC + kk);
        bf16x8 blf = ldg8(qt_lo + (bN + m) * CC + kk);
        #pragma unroll
        for (int t = 0; t < 3; ++t) {
            int rowH = t * 16 + lr;
            bf16x8 ahh = ldg8(relhT_hi + rowH * CC + kk);
            bf16x8 ahl = ldg8(relhT_lo + rowH * CC + kk);
            acc[t] = MFMA(ahh, bhf, acc[t]);
            acc[t] = MFMA(ahl, bhf, acc[t]);
            acc[t] = MFMA(ahh, blf, acc[t]);
            bf16x8 awh = ldg8(relwT_hi + rowH * CC + kk);
            bf16x8 awl = ldg8(relwT_lo + rowH * CC + kk);
            acc[3 + t] = MFMA(awh, bhf, acc[3 + t]);
            acc[3 + t] = MFMA(awl, bhf, acc[3 + t]);
            acc[3 + t] = MFMA(awh, blf, acc[3 + t]);
        }
    }
    #pragma unroll
    for (int t = 0; t < 3; ++t) {
        #pragma unroll
        for (int r = 0; r < 4; ++r) {
            int h = t * 16 + lg * 4 + r;
            rhq[((size_t)b * HH + h) * NN + m] = acc[t][r];
            rwq[((size_t)b * HH + h) * NN + m] = acc[3 + t][r];
        }
    }
}

// ---- flash attention: 1 block = 128 rows (8 waves x 16), m-tiles of 64 ----
// R6 grid (288 blocks, natural 2-D order). Counted-vmcnt pipeline: per phase
// issue [V-quarter, K-hi, K-lo] then s_waitcnt vmcnt(3) (prev trio done, this
// trio in flight) + raw s_barrier; MFMAs; exit barrier. Tile end: vmcnt(2)
// (V landed, next-tile K stays in flight) + barrier; PV from LDS; lgkmcnt(0)
// + barrier. No vmcnt(0) drain anywhere in the main loop.
__global__ __launch_bounds__(512, 2) void k_attn(
        const __hip_bfloat16* __restrict__ qt_hi, const __hip_bfloat16* __restrict__ qt_lo,
        const __hip_bfloat16* __restrict__ kt_hi, const __hip_bfloat16* __restrict__ kt_lo,
        const float* __restrict__ rhq, const float* __restrict__ rwq,
        const __hip_bfloat16* __restrict__ vbuf, float* __restrict__ out) {
    __shared__ __align__(16) __hip_bfloat16 lds_k[2][2][64][64];  // [buf][plane][row][k] 32KB
    __shared__ __align__(16) __hip_bfloat16 lds_v[256][64];       // [c][m] 32KB (swizzled)
    __shared__ __align__(16) __hip_bfloat16 lds_p[8][16][64];     // per-wave P tile 16KB (swizzled)
    int b = blockIdx.y;
    int n0 = blockIdx.x * 128;
    int wave = threadIdx.x >> 6, lane = threadIdx.x & 63;
    int lr = lane & 15, lg = lane >> 4;
    int rowA = n0 + wave * 16 + lr;
    const size_t bN = (size_t)b * NN;

    // Q fragments in registers: 16 rows x 256 k per wave, hi+lo
    bf16x8 qh[8], ql[8];
    #pragma unroll
    for (int ks = 0; ks < 8; ++ks) {
        int kk = ks * 32 + lg * 8;
        qh[ks] = ldg8(qt_hi + (bN + rowA) * CC + kk);
        ql[ks] = ldg8(qt_lo + (bN + rowA) * CC + kk);
    }
    // pos-table row indices for this lane's 4 output rows
    int hn[4], wn[4];
    #pragma unroll
    for (int r = 0; r < 4; ++r) {
        int n = n0 + wave * 16 + lg * 4 + r;
        hn[r] = n % HH;
        wn[r] = n / HH;
    }
    const float* rhq_b = rhq + (size_t)b * HH * NN;
    const float* rwq_b = rwq + (size_t)b * HH * NN;

    f32x4 oacc[16] = {};
    float mrun[4] = {-1e30f, -1e30f, -1e30f, -1e30f};
    float lrun[4] = {0.f, 0.f, 0.f, 0.f};

    // staging: LDS dest linear (lane*16B); global source chunk pre-swizzled so
    // logical chunk c of row r lands at physical chunk c^(r&7).
    int srl = lane >> 3;                      // row within wave's 8-row group
    int sch = ((lane & 7) ^ srl) * 8;         // pre-swizzled source k-offset (elems)
    auto STAGE_K = [&](int buf, int m0s, int k0) {
        int grow = m0s + wave * 8 + srl;
        const __hip_bfloat16* sH = kt_hi + (bN + grow) * CC + k0 + sch;
        const __hip_bfloat16* sL = kt_lo + (bN + grow) * CC + k0 + sch;
        gload_lds16(sH, &lds_k[buf][0][wave * 8][0]);
        gload_lds16(sL, &lds_k[buf][1][wave * 8][0]);
    };
    auto STAGE_V = [&](int q, int m0s) {       // quarter q: c-rows [q*64, q*64+64)
        int crow = q * 64 + wave * 8 + srl;
        const __hip_bfloat16* sV = vbuf + ((size_t)b * CC + crow) * NN + m0s + sch;
        gload_lds16(sV, &lds_v[q * 64 + wave * 8][0]);
    };

    STAGE_K(0, 0, 0);
    WAITV(0);
    BAR();

    for (int t = 0; t < 36; ++t) {
        int m0 = t * 64;
        // pos adds — issued here, drained by phase-0's vmcnt(3) (they're older)
        float padd[4][4];
        #pragma unroll
        for (int mt = 0; mt < 4; ++mt) {
            int m = m0 + mt * 16 + lr;
            #pragma unroll
            for (int r = 0; r < 4; ++r)
                padd[mt][r] = rhq_b[(size_t)hn[r] * NN + m] + rwq_b[(size_t)wn[r] * NN + m];
        }
        // ---- S tile [16n x 64m], K=256 in 4 phases of 64, 3-pass split ----
        f32x4 sacc[4] = {};
        #pragma unroll
        for (int s = 0; s < 4; ++s) {
            // issue order matters for vmcnt counting: V first, then K pair
            STAGE_V(s, m0);
            if (s < 3) STAGE_K((s + 1) & 1, m0, (s + 1) * 64);
            else       STAGE_K(0, m0 + 64, 0);   // t=35: garbage-in-bounds, unused
            WAITV(3);        // prev phase's trio landed; this trio in flight
            BAR();           // all waves' slice-s K data visible in LDS
            #pragma unroll
            for (int ks = 0; ks < 2; ++ks) {
                #pragma unroll
                for (int mt = 0; mt < 4; ++mt) {
                    int row = mt * 16 + lr;
                    int ch = ((ks * 4 + lg) ^ (lr & 7)) * 8;   // swizzled read
                    bf16x8 bh = *reinterpret_cast<const bf16x8*>(&lds_k[s & 1][0][row][ch]);
                    bf16x8 bl = *reinterpret_cast<const bf16x8*>(&lds_k[s & 1][1][row][ch]);
                    sacc[mt] = MFMA(qh[s * 2 + ks], bh, sacc[mt]);
                    sacc[mt] = MFMA(qh[s * 2 + ks], bl, sacc[mt]);
                    sacc[mt] = MFMA(ql[s * 2 + ks], bh, sacc[mt]);
                }
            }
            if (s < 3) BAR();   // reads of buf done before next phase overwrites
        }
        // ---- add pos term, online softmax (register-only) ----
        #pragma unroll
        for (int mt = 0; mt < 4; ++mt)
            #pragma unroll
            for (int r = 0; r < 4; ++r)
                sacc[mt][r] += padd[mt][r];
        #pragma unroll
        for (int r = 0; r < 4; ++r) {
            float smax = fmaxf(fmaxf(sacc[0][r], sacc[1][r]), fmaxf(sacc[2][r], sacc[3][r]));
            #pragma unroll
            for (int mk = 1; mk <= 8; mk <<= 1)
                smax = fmaxf(smax, __shfl_xor(smax, mk));
            float mnew = fmaxf(mrun[r], smax);
            float scale = __expf(mrun[r] - mnew);
            float rsum = 0.f;
            #pragma unroll
            for (int mt = 0; mt < 4; ++mt) {
                float p = __expf(sacc[mt][r] - mnew);
                sacc[mt][r] = p;
                rsum += p;
            }
            #pragma unroll
            for (int mk = 1; mk <= 8; mk <<= 1)
                rsum += __shfl_xor(rsum, mk);
            lrun[r] = lrun[r] * scale + rsum;
            mrun[r] = mnew;
            #pragma unroll
            for (int ct = 0; ct < 16; ++ct) oacc[ct][r] *= scale;
        }
        // ---- P -> LDS (transpose for PV A-frags), wave-private, XOR-swizzled
        #pragma unroll
        for (int mt = 0; mt < 4; ++mt) {
            #pragma unroll
            for (int r = 0; r < 4; ++r) {
                int prow = lg * 4 + r;
                int pcol = mt * 16 + lr;
                int pcol_s = (((pcol >> 3) ^ (prow & 7)) << 3) | (pcol & 7);
                lds_p[wave][prow][pcol_s] = __float2bfloat16(sacc[mt][r]);
            }
        }
        WAITV(2);   // all 4 V quarters landed; 2 next-tile K loads stay in flight
        BAR();
        // ---- PV from LDS: out_t[n][c] += sum_m P[n][m] * v[c][m] ----
        #pragma unroll
        for (int ks2 = 0; ks2 < 2; ++ks2) {
            int pch = ((ks2 * 4 + lg) ^ (lr & 7)) * 8;         // swizzled read
            bf16x8 pa = *reinterpret_cast<const bf16x8*>(&lds_p[wave][lr][pch]);
            #pragma unroll
            for (int ct = 0; ct < 16; ++ct) {
                int vrow = ct * 16 + lr;
                bf16x8 bvv = *reinterpret_cast<const bf16x8*>(&lds_v[vrow][pch]);
                oacc[ct] = MFMA(pa, bvv, oacc[ct]);
            }
        }
        WAITL();    // PV lds reads complete before next tile's V restage
        BAR();
    }
    // ---- epilogue: normalize and store out[b][c][n] ----
    #pragma unroll
    for (int ct = 0; ct < 16; ++ct) {
        int c = ct * 16 + lr;
        #pragma unroll
        for (int r = 0; r < 4; ++r) {
            int n = n0 + wave * 16 + lg * 4 + r;
            out[((size_t)b * CC + c) * NN + n] = oacc[ct][r] / lrun[r];
        }
    }
}

extern "C" void kernel_launch(void* const* d_in, const int* in_sizes, int n_in,
                              void* d_out, int out_size, void* d_ws, size_t ws_size,
                              hipStream_t stream) {
    const float* x     = (const float*)d_in[0];
    const float* Wq    = (const float*)d_in[1];
    const float* bq    = (const float*)d_in[2];
    const float* Wk    = (const float*)d_in[3];
    const float* bk    = (const float*)d_in[4];
    const float* Wv    = (const float*)d_in[5];
    const float* bv    = (const float*)d_in[6];
    const float* rel_h = (const float*)d_in[7];
    const float* rel_w = (const float*)d_in[8];
    float* out = (float*)d_out;

    size_t off = 0;
    auto carve = [&](size_t bytes) {
        void* p = (char*)d_ws + off;
        off += (bytes + 255) & ~(size_t)255;
        return p;
    };
    const size_t sz_t = (size_t)BB * NN * CC * sizeof(__hip_bfloat16);
    __hip_bfloat16* xt_hi  = (__hip_bfloat16*)carve(sz_t);
    __hip_bfloat16* xt_lo  = (__hip_bfloat16*)carve(sz_t);
    __hip_bfloat16* qt_hi  = (__hip_bfloat16*)carve(sz_t);
    __hip_bfloat16* qt_lo  = (__hip_bfloat16*)carve(sz_t);
    __hip_bfloat16* kt_hi  = (__hip_bfloat16*)carve(sz_t);
    __hip_bfloat16* kt_lo  = (__hip_bfloat16*)carve(sz_t);
    __hip_bfloat16* vbuf   = (__hip_bfloat16*)carve(sz_t);
    __hip_bfloat16* relhT_hi = (__hip_bfloat16*)carve((size_t)HH * CC * 2);
    __hip_bfloat16* relhT_lo = (__hip_bfloat16*)carve((size_t)HH * CC * 2);
    __hip_bfloat16* relwT_hi = (__hip_bfloat16*)carve((size_t)HH * CC * 2);
    __hip_bfloat16* relwT_lo = (__hip_bfloat16*)carve((size_t)HH * CC * 2);
    __hip_bfloat16* w_hi   = (__hip_bfloat16*)carve((size_t)3 * CC * CC * 2);
    __hip_bfloat16* w_lo   = (__hip_bfloat16*)carve((size_t)3 * CC * CC * 2);
    float* rhq = (float*)carve((size_t)BB * HH * NN * 4);
    float* rwq = (float*)carve((size_t)BB * HH * NN * 4);
    if (off > ws_size) return;   // workspace too small -> output stays poisoned (visible failure)

    k_prep_x<<<dim3(NN / 64, CC / 64, BB), 256, 0, stream>>>(x, xt_hi, xt_lo);
    k_prep_w<<<dim3(3 * CC * CC / 256), 256, 0, stream>>>(Wq, Wk, Wv, w_hi, w_lo);
    k_prep_rel<<<dim3(HH * CC / 256), 256, 0, stream>>>(rel_h, rel_w,
        relhT_hi, relhT_lo, relwT_hi, relwT_lo);
    k_proj<<<dim3((NN / 64) * (CC / 64), BB, 3), 256, 0, stream>>>(
        xt_hi, xt_lo, w_hi, w_lo, bq, bk, bv, qt_hi, qt_lo, kt_hi, kt_lo, vbuf);
    k_posq<<<dim3(NN / 64, BB), 256, 0, stream>>>(
        qt_hi, qt_lo, relhT_hi, relhT_lo, relwT_hi, relwT_lo, rhq, rwq);
    k_attn<<<dim3(NN / 128, BB), 512, 0, stream>>>(
        qt_hi, qt_lo, kt_hi, kt_lo, rhq, rwq, vbuf, out);
}

// Round 11
// 724.353 us; speedup vs baseline: 1.2907x; 1.2472x over previous
//
#include <hip/hip_runtime.h>
#include <hip/hip_bf16.h>

// MHSA: B=16, C=256, H=W=48, N=2304.
// S[b,n,m] = q[b,:,n]·k[b,:,m] + rhq[b][n%48][m] + rwq[b][n/48][m]
// att = softmax_m(S); out[b,c,n] = sum_m v[b,c,m] att[n,m]
// fp32-accurate logits: 3-pass split-bf16 (qh·kh + qh·kl + ql·kh).
//   R10 lesson: dropping qh·kl fails (absmax 0.172 > 0.104) — restored.
//
// Structure (R11): R6-proven grid (288 blk x 8 waves x 128 rows) + sync
// (__syncthreads; R9 showed asm-barrier grafts regress). PV n-major from R10:
// P shared in LDS, wave owns [64n x 64c] -> PV reads 34->16. LDS = K 32K +
// V 32K + P 16K = 80KB exactly (2 blk/CU); per-tile scale + epilogue lrun are
// ALIASED into lds_k[1] (dead between ph3-consume and next-tile ph0 restage).

#define BB 16
#define CC 256
#define HH 48
#define NN 2304

typedef float f32x4 __attribute__((ext_vector_type(4)));
typedef short bf16x8 __attribute__((ext_vector_type(8)));

#define MFMA(a, b, c) __builtin_amdgcn_mfma_f32_16x16x32_bf16((a), (b), (c), 0, 0, 0)

__device__ inline bf16x8 ldg8(const __hip_bfloat16* p) {
    return *reinterpret_cast<const bf16x8*>(p);
}

typedef __attribute__((address_space(3))) unsigned int lds_uint;
typedef const __attribute__((address_space(1))) unsigned int gbl_uint;

__device__ inline void gload_lds16(const __hip_bfloat16* g, __hip_bfloat16* l) {
    __builtin_amdgcn_global_load_lds((gbl_uint*)g, (lds_uint*)l, 16, 0, 0);
}

// ---- prep: transpose x [b][c][n] -> xT [b][n][c], split into bf16 hi/lo ----
__global__ __launch_bounds__(256) void k_prep_x(const float* __restrict__ x,
        __hip_bfloat16* __restrict__ xt_hi, __hip_bfloat16* __restrict__ xt_lo) {
    __shared__ float tile[64][65];
    int b = blockIdx.z, n0 = blockIdx.x * 64, c0 = blockIdx.y * 64;
    const float* xb = x + (size_t)b * CC * NN;
    #pragma unroll
    for (int i = 0; i < 16; ++i) {
        int idx = i * 256 + threadIdx.x;
        int r = idx >> 6, col = idx & 63;
        tile[r][col] = xb[(size_t)(c0 + r) * NN + n0 + col];
    }
    __syncthreads();
    #pragma unroll
    for (int i = 0; i < 16; ++i) {
        int idx = i * 256 + threadIdx.x;
        int r = idx >> 6, col = idx & 63;           // r = n-local, col = c-local
        float v = tile[col][r];
        __hip_bfloat16 h = __float2bfloat16(v);
        size_t o = ((size_t)b * NN + n0 + r) * CC + c0 + col;
        xt_hi[o] = h;
        xt_lo[o] = __float2bfloat16(v - __bfloat162float(h));
    }
}

// ---- prep: split Wq/Wk/Wv into hi/lo (layout [3][256][256] row-major) ----
__global__ __launch_bounds__(256) void k_prep_w(const float* __restrict__ Wq,
        const float* __restrict__ Wk, const float* __restrict__ Wv,
        __hip_bfloat16* __restrict__ w_hi, __hip_bfloat16* __restrict__ w_lo) {
    int i = blockIdx.x * 256 + threadIdx.x;         // < 3*65536
    int m = i >> 16, j = i & 65535;
    const float* W = (m == 0) ? Wq : ((m == 1) ? Wk : Wv);
    float v = W[j];
    __hip_bfloat16 h = __float2bfloat16(v);
    w_hi[i] = h;
    w_lo[i] = __float2bfloat16(v - __bfloat162float(h));
}

// ---- prep: relhT[h][c] = rel_h[c][h], relwT[w][c] = rel_w[c][w], hi/lo split
__global__ __launch_bounds__(256) void k_prep_rel(const float* __restrict__ rel_h,
        const float* __restrict__ rel_w,
        __hip_bfloat16* __restrict__ relhT_hi, __hip_bfloat16* __restrict__ relhT_lo,
        __hip_bfloat16* __restrict__ relwT_hi, __hip_bfloat16* __restrict__ relwT_lo) {
    int i = blockIdx.x * 256 + threadIdx.x;         // < 48*256
    int h = i >> 8, c = i & 255;
    float vh = rel_h[c * HH + h];
    float vw = rel_w[c * HH + h];
    __hip_bfloat16 hh = __float2bfloat16(vh);
    relhT_hi[i] = hh;
    relhT_lo[i] = __float2bfloat16(vh - __bfloat162float(hh));
    __hip_bfloat16 hw = __float2bfloat16(vw);
    relwT_hi[i] = hw;
    relwT_lo[i] = __float2bfloat16(vw - __bfloat162float(hw));
}

// ---- projection GEMM: yT[b][n][o] = sum_c xT[b][n][c] * W[o][c] + bias[o] ----
// pj=0 -> qT hi/lo, pj=1 -> kT hi/lo, pj=2 -> v[b][o][n] bf16
__global__ __launch_bounds__(256) void k_proj(
        const __hip_bfloat16* __restrict__ xt_hi, const __hip_bfloat16* __restrict__ xt_lo,
        const __hip_bfloat16* __restrict__ w_hi,  const __hip_bfloat16* __restrict__ w_lo,
        const float* __restrict__ bq, const float* __restrict__ bk, const float* __restrict__ bv,
        __hip_bfloat16* __restrict__ qt_hi, __hip_bfloat16* __restrict__ qt_lo,
        __hip_bfloat16* __restrict__ kt_hi, __hip_bfloat16* __restrict__ kt_lo,
        __hip_bfloat16* __restrict__ vbuf) {
    int b = blockIdx.y, pj = blockIdx.z;
    int n0 = (blockIdx.x >> 2) * 64, o0 = (blockIdx.x & 3) * 64;
    int wave = threadIdx.x >> 6, lane = threadIdx.x & 63;
    int lr = lane & 15, lg = lane >> 4;
    int rowA = n0 + wave * 16 + lr;
    const __hip_bfloat16* wh = w_hi + (size_t)pj * 65536;
    const __hip_bfloat16* wl = w_lo + (size_t)pj * 65536;
    const __hip_bfloat16* axh = xt_hi + ((size_t)b * NN + rowA) * CC;
    const __hip_bfloat16* axl = xt_lo + ((size_t)b * NN + rowA) * CC;
    f32x4 acc[4] = {};
    #pragma unroll
    for (int ks = 0; ks < 8; ++ks) {
        int kk = ks * 32 + lg * 8;
        bf16x8 ah = ldg8(axh + kk);
        bf16x8 al = ldg8(axl + kk);
        #pragma unroll
        for (int ot = 0; ot < 4; ++ot) {
            int rowB = o0 + ot * 16 + lr;
            bf16x8 bh = ldg8(wh + rowB * CC + kk);
            bf16x8 bl = ldg8(wl + rowB * CC + kk);
            acc[ot] = MFMA(ah, bh, acc[ot]);
            acc[ot] = MFMA(ah, bl, acc[ot]);
            acc[ot] = MFMA(al, bh, acc[ot]);
        }
    }
    const float* bias = (pj == 0) ? bq : ((pj == 1) ? bk : bv);
    #pragma unroll
    for (int ot = 0; ot < 4; ++ot) {
        int o = o0 + ot * 16 + lr;
        float bb = bias[o];
        #pragma unroll
        for (int r = 0; r < 4; ++r) {
            int n = n0 + wave * 16 + lg * 4 + r;
            float y = acc[ot][r] + bb;
            if (pj == 0) {
                __hip_bfloat16 h = __float2bfloat16(y);
                size_t off = ((size_t)b * NN + n) * CC + o;
                qt_hi[off] = h;
                qt_lo[off] = __float2bfloat16(y - __bfloat162float(h));
            } else if (pj == 1) {
                __hip_bfloat16 h = __float2bfloat16(y);
                size_t off = ((size_t)b * NN + n) * CC + o;
                kt_hi[off] = h;
                kt_lo[off] = __float2bfloat16(y - __bfloat162float(h));
            } else {
                vbuf[((size_t)b * CC + o) * NN + n] = __float2bfloat16(y);
            }
        }
    }
}

// ---- pos rank-split: rhq[b][h][m] = sum_c relhT[h][c] q[b][c][m]; same for rwq
__global__ __launch_bounds__(256) void k_posq(
        const __hip_bfloat16* __restrict__ qt_hi, const __hip_bfloat16* __restrict__ qt_lo,
        const __hip_bfloat16* __restrict__ relhT_hi, const __hip_bfloat16* __restrict__ relhT_lo,
        const __hip_bfloat16* __restrict__ relwT_hi, const __hip_bfloat16* __restrict__ relwT_lo,
        float* __restrict__ rhq, float* __restrict__ rwq) {
    int b = blockIdx.y, m0 = blockIdx.x * 64;
    int wave = threadIdx.x >> 6, lane = threadIdx.x & 63;
    int lr = lane & 15, lg = lane >> 4;
    int m = m0 + wave * 16 + lr;                    // output column
    const size_t bN = (size_t)b * NN;
    f32x4 acc[6] = {};                              // 3 h-tiles rh, 3 w-tiles rw
    #pragma unroll
    for (int ks = 0; ks < 8; ++ks) {
        int kk = ks * 32 + lg * 8;
        bf16x8 bhf = ldg8(qt_hi + (bN + m) * CC + kk);
        bf16x8 blf = ldg8(qt_lo + (bN + m) * CC + kk);
        #pragma unroll
        for (int t = 0; t < 3; ++t) {
            int rowH = t * 16 + lr;
            bf16x8 ahh = ldg8(relhT_hi + rowH * CC + kk);
            bf16x8 ahl = ldg8(relhT_lo + rowH * CC + kk);
            acc[t] = MFMA(ahh, bhf, acc[t]);
            acc[t] = MFMA(ahl, bhf, acc[t]);
            acc[t] = MFMA(ahh, blf, acc[t]);
            bf16x8 awh = ldg8(relwT_hi + rowH * CC + kk);
            bf16x8 awl = ldg8(relwT_lo + rowH * CC + kk);
            acc[3 + t] = MFMA(awh, bhf, acc[3 + t]);
            acc[3 + t] = MFMA(awl, bhf, acc[3 + t]);
            acc[3 + t] = MFMA(awh, blf, acc[3 + t]);
        }
    }
    #pragma unroll
    for (int t = 0; t < 3; ++t) {
        #pragma unroll
        for (int r = 0; r < 4; ++r) {
            int h = t * 16 + lg * 4 + r;
            rhq[((size_t)b * HH + h) * NN + m] = acc[t][r];
            rwq[((size_t)b * HH + h) * NN + m] = acc[3 + t][r];
        }
    }
}

// ---- flash attention: 1 block = 128 rows (8 waves x 16), m-tiles of 64 ----
// S: wave w owns q-rows 16w.. (Q hi/lo regs, K hi/lo LDS, 3-pass). Softmax per
// S-wave; P + per-row scale shared via LDS (scale aliased into dead lds_k[1]).
// PV n-major: wave w owns [64n x 64c] (nh=w>>2, cq=w&3). XOR swizzle on all
// staged tiles (conflict-free, measured). R6 sync structure (proven 437us).
__global__ __launch_bounds__(512, 2) void k_attn(
        const __hip_bfloat16* __restrict__ qt_hi, const __hip_bfloat16* __restrict__ qt_lo,
        const __hip_bfloat16* __restrict__ kt_hi, const __hip_bfloat16* __restrict__ kt_lo,
        const float* __restrict__ rhq, const float* __restrict__ rwq,
        const __hip_bfloat16* __restrict__ vbuf, float* __restrict__ out) {
    __shared__ __align__(16) __hip_bfloat16 lds_k[2][2][64][64];  // [buf][plane][row][k] 32KB
    __shared__ __align__(16) __hip_bfloat16 lds_v[256][64];       // [c][m] 32KB (swizzled)
    __shared__ __align__(16) __hip_bfloat16 lds_p[128][64];       // shared P tile 16KB (swizzled)
    // scale/lrun aliased into lds_k[1]: dead from ph3-consume until next-tile
    // ph0 restage (which happens after the PV-end barrier). 1KB of 16KB used.
    float* lds_scale = reinterpret_cast<float*>(&lds_k[1][0][0][0]);
    float* lds_lrun  = lds_scale + 128;
    int b = blockIdx.y;
    int n0 = blockIdx.x * 128;
    int wave = threadIdx.x >> 6, lane = threadIdx.x & 63;
    int lr = lane & 15, lg = lane >> 4;
    int rowA = n0 + wave * 16 + lr;
    const size_t bN = (size_t)b * NN;

    // Q fragments in registers: 16 rows x 256 k per wave, hi+lo
    bf16x8 qh[8], ql[8];
    #pragma unroll
    for (int ks = 0; ks < 8; ++ks) {
        int kk = ks * 32 + lg * 8;
        qh[ks] = ldg8(qt_hi + (bN + rowA) * CC + kk);
        ql[ks] = ldg8(qt_lo + (bN + rowA) * CC + kk);
    }
    // pos-table row indices for this lane's 4 softmax rows
    int hn[4], wn[4];
    #pragma unroll
    for (int r = 0; r < 4; ++r) {
        int n = n0 + wave * 16 + lg * 4 + r;
        hn[r] = n % HH;
        wn[r] = n / HH;
    }
    const float* rhq_b = rhq + (size_t)b * HH * NN;
    const float* rwq_b = rwq + (size_t)b * HH * NN;

    // PV ownership: [64n x 64c] per wave
    int nh = wave >> 2;                 // n-half: rows nh*64 .. +63
    int cq = wave & 3;                  // c-quarter: cols cq*64 .. +63
    f32x4 oacc[4][4] = {};              // [nf][cf]
    float mrun[4] = {-1e30f, -1e30f, -1e30f, -1e30f};
    float lrun[4] = {0.f, 0.f, 0.f, 0.f};

    // staging: LDS dest linear (lane*16B); global source chunk pre-swizzled so
    // logical chunk c of row r lands at physical chunk c^(r&7).
    int srl = lane >> 3;                      // row within wave's 8-row group
    int sch = ((lane & 7) ^ srl) * 8;         // pre-swizzled source k-offset (elems)
    auto STAGE_K = [&](int buf, int m0s, int k0) {
        int grow = m0s + wave * 8 + srl;
        gload_lds16(kt_hi + (bN + grow) * CC + k0 + sch, &lds_k[buf][0][wave * 8][0]);
        gload_lds16(kt_lo + (bN + grow) * CC + k0 + sch, &lds_k[buf][1][wave * 8][0]);
    };
    auto STAGE_V = [&](int q, int m0s) {       // quarter q: c-rows [q*64, q*64+64)
        int crow = q * 64 + wave * 8 + srl;
        gload_lds16(vbuf + ((size_t)b * CC + crow) * NN + m0s + sch, &lds_v[q * 64 + wave * 8][0]);
    };

    int cur = 0;
    STAGE_K(0, 0, 0);
    __syncthreads();

    for (int t = 0; t < 36; ++t) {
        int m0 = t * 64;
        // pos adds (issued early; consumed after 4 phases — hidden)
        float padd[4][4];
        #pragma unroll
        for (int mt = 0; mt < 4; ++mt) {
            int m = m0 + mt * 16 + lr;
            #pragma unroll
            for (int r = 0; r < 4; ++r)
                padd[mt][r] = rhq_b[(size_t)hn[r] * NN + m] + rwq_b[(size_t)wn[r] * NN + m];
        }
        // ---- S tile [16n x 64m], K=256 in 4 phases of 64, 3-pass split ----
        // buf trace (cur=0 at tile start): ph0 reads 0 stages 1; ph1 reads 1
        // stages 0; ph2 reads 0 stages 1; ph3 reads 1 stages 0 (next tile).
        // => during PV, buf1 is dead (scale alias target), buf0 holds t+1 data.
        f32x4 sacc[4] = {};
        #pragma unroll
        for (int ph = 0; ph < 4; ++ph) {
            if (ph < 3) STAGE_K(cur ^ 1, m0, (ph + 1) * 64);
            else if (t + 1 < 36) STAGE_K(cur ^ 1, m0 + 64, 0);
            STAGE_V(ph, m0);                       // quarter ph of current tile
            #pragma unroll
            for (int ks = 0; ks < 2; ++ks) {
                #pragma unroll
                for (int mt = 0; mt < 4; ++mt) {
                    int row = mt * 16 + lr;
                    int ch = ((ks * 4 + lg) ^ (lr & 7)) * 8;   // swizzled read
                    bf16x8 bh = *reinterpret_cast<const bf16x8*>(&lds_k[cur][0][row][ch]);
                    bf16x8 bl = *reinterpret_cast<const bf16x8*>(&lds_k[cur][1][row][ch]);
                    sacc[mt] = MFMA(qh[ph * 2 + ks], bh, sacc[mt]);
                    sacc[mt] = MFMA(qh[ph * 2 + ks], bl, sacc[mt]);
                    sacc[mt] = MFMA(ql[ph * 2 + ks], bh, sacc[mt]);
                }
            }
            __syncthreads();
            cur ^= 1;
        }
        // ---- add pos term, online softmax (per S-wave rows) ----
        #pragma unroll
        for (int mt = 0; mt < 4; ++mt)
            #pragma unroll
            for (int r = 0; r < 4; ++r)
                sacc[mt][r] += padd[mt][r];
        float scl_r[4];
        #pragma unroll
        for (int r = 0; r < 4; ++r) {
            float smax = fmaxf(fmaxf(sacc[0][r], sacc[1][r]), fmaxf(sacc[2][r], sacc[3][r]));
            #pragma unroll
            for (int mk = 1; mk <= 8; mk <<= 1)
                smax = fmaxf(smax, __shfl_xor(smax, mk));
            float mnew = fmaxf(mrun[r], smax);
            scl_r[r] = __expf(mrun[r] - mnew);
            float rsum = 0.f;
            #pragma unroll
            for (int mt = 0; mt < 4; ++mt) {
                float p = __expf(sacc[mt][r] - mnew);
                sacc[mt][r] = p;
                rsum += p;
            }
            #pragma unroll
            for (int mk = 1; mk <= 8; mk <<= 1)
                rsum += __shfl_xor(rsum, mk);
            lrun[r] = lrun[r] * scl_r[r] + rsum;
            mrun[r] = mnew;
        }
        // ---- P + scale -> shared LDS (XOR-swizzled P; scale into dead buf1)
        #pragma unroll
        for (int mt = 0; mt < 4; ++mt) {
            #pragma unroll
            for (int r = 0; r < 4; ++r) {
                int prow = wave * 16 + lg * 4 + r;
                int pcol = mt * 16 + lr;
                int pcol_s = (((pcol >> 3) ^ (prow & 7)) << 3) | (pcol & 7);
                lds_p[prow][pcol_s] = __float2bfloat16(sacc[mt][r]);
            }
        }
        if (lr == 0) {
            #pragma unroll
            for (int r = 0; r < 4; ++r)
                lds_scale[wave * 16 + lg * 4 + r] = scl_r[r];
        }
        __syncthreads();   // P, scale, and all 4 V quarters visible
        // ---- PV: wave computes [64n x 64c]; rescale then accumulate ----
        f32x4 scl4[4];
        #pragma unroll
        for (int nf = 0; nf < 4; ++nf) {
            scl4[nf] = *reinterpret_cast<const f32x4*>(&lds_scale[nh * 64 + nf * 16 + lg * 4]);
            #pragma unroll
            for (int cf = 0; cf < 4; ++cf)
                oacc[nf][cf] *= scl4[nf];
        }
        #pragma unroll
        for (int ks2 = 0; ks2 < 2; ++ks2) {
            bf16x8 pa[4];
            #pragma unroll
            for (int nf = 0; nf < 4; ++nf) {
                int prow = nh * 64 + nf * 16 + lr;
                int pch = ((ks2 * 4 + lg) ^ (lr & 7)) * 8;
                pa[nf] = *reinterpret_cast<const bf16x8*>(&lds_p[prow][pch]);
            }
            #pragma unroll
            for (int cf = 0; cf < 4; ++cf) {
                int vrow = cq * 64 + cf * 16 + lr;
                int vch = ((ks2 * 4 + lg) ^ (lr & 7)) * 8;
                bf16x8 bv = *reinterpret_cast<const bf16x8*>(&lds_v[vrow][vch]);
                #pragma unroll
                for (int nf = 0; nf < 4; ++nf)
                    oacc[nf][cf] = MFMA(pa[nf], bv, oacc[nf][cf]);
            }
        }
        __syncthreads();   // PV reads (incl. scale in buf1) done before restage
    }
    // ---- epilogue: publish lrun (dead LDS), each PV-wave normalizes+stores
    if (lr == 0) {
        #pragma unroll
        for (int r = 0; r < 4; ++r)
            lds_lrun[wave * 16 + lg * 4 + r] = lrun[r];
    }
    __syncthreads();
    #pragma unroll
    for (int nf = 0; nf < 4; ++nf) {
        f32x4 lr4 = *reinterpret_cast<const f32x4*>(&lds_lrun[nh * 64 + nf * 16 + lg * 4]);
        int nbase = n0 + nh * 64 + nf * 16 + lg * 4;
        #pragma unroll
        for (int cf = 0; cf < 4; ++cf) {
            int c = cq * 64 + cf * 16 + lr;
            f32x4 o = oacc[nf][cf] / lr4;
            *reinterpret_cast<f32x4*>(&out[((size_t)b * CC + c) * NN + nbase]) = o;
        }
    }
}

extern "C" void kernel_launch(void* const* d_in, const int* in_sizes, int n_in,
                              void* d_out, int out_size, void* d_ws, size_t ws_size,
                              hipStream_t stream) {
    const float* x     = (const float*)d_in[0];
    const float* Wq    = (const float*)d_in[1];
    const float* bq    = (const float*)d_in[2];
    const float* Wk    = (const float*)d_in[3];
    const float* bk    = (const float*)d_in[4];
    const float* Wv    = (const float*)d_in[5];
    const float* bv    = (const float*)d_in[6];
    const float* rel_h = (const float*)d_in[7];
    const float* rel_w = (const float*)d_in[8];
    float* out = (float*)d_out;

    size_t off = 0;
    auto carve = [&](size_t bytes) {
        void* p = (char*)d_ws + off;
        off += (bytes + 255) & ~(size_t)255;
        return p;
    };
    const size_t sz_t = (size_t)BB * NN * CC * sizeof(__hip_bfloat16);
    __hip_bfloat16* xt_hi  = (__hip_bfloat16*)carve(sz_t);
    __hip_bfloat16* xt_lo  = (__hip_bfloat16*)carve(sz_t);
    __hip_bfloat16* qt_hi  = (__hip_bfloat16*)carve(sz_t);
    __hip_bfloat16* qt_lo  = (__hip_bfloat16*)carve(sz_t);
    __hip_bfloat16* kt_hi  = (__hip_bfloat16*)carve(sz_t);
    __hip_bfloat16* kt_lo  = (__hip_bfloat16*)carve(sz_t);
    __hip_bfloat16* vbuf   = (__hip_bfloat16*)carve(sz_t);
    __hip_bfloat16* relhT_hi = (__hip_bfloat16*)carve((size_t)HH * CC * 2);
    __hip_bfloat16* relhT_lo = (__hip_bfloat16*)carve((size_t)HH * CC * 2);
    __hip_bfloat16* relwT_hi = (__hip_bfloat16*)carve((size_t)HH * CC * 2);
    __hip_bfloat16* relwT_lo = (__hip_bfloat16*)carve((size_t)HH * CC * 2);
    __hip_bfloat16* w_hi   = (__hip_bfloat16*)carve((size_t)3 * CC * CC * 2);
    __hip_bfloat16* w_lo   = (__hip_bfloat16*)carve((size_t)3 * CC * CC * 2);
    float* rhq = (float*)carve((size_t)BB * HH * NN * 4);
    float* rwq = (float*)carve((size_t)BB * HH * NN * 4);
    if (off > ws_size) return;   // workspace too small -> output stays poisoned (visible failure)

    k_prep_x<<<dim3(NN / 64, CC / 64, BB), 256, 0, stream>>>(x, xt_hi, xt_lo);
    k_prep_w<<<dim3(3 * CC * CC / 256), 256, 0, stream>>>(Wq, Wk, Wv, w_hi, w_lo);
    k_prep_rel<<<dim3(HH * CC / 256), 256, 0, stream>>>(rel_h, rel_w,
        relhT_hi, relhT_lo, relwT_hi, relwT_lo);
    k_proj<<<dim3((NN / 64) * (CC / 64), BB, 3), 256, 0, stream>>>(
        xt_hi, xt_lo, w_hi, w_lo, bq, bk, bv, qt_hi, qt_lo, kt_hi, kt_lo, vbuf);
    k_posq<<<dim3(NN / 64, BB), 256, 0, stream>>>(
        qt_hi, qt_lo, relhT_hi, relhT_lo, relwT_hi, relwT_lo, rhq, rwq);
    k_attn<<<dim3(NN / 128, BB), 512, 0, stream>>>(
        qt_hi, qt_lo, kt_hi, kt_lo, rhq, rwq, vbuf, out);
}

// Round 12
// 677.864 us; speedup vs baseline: 1.3792x; 1.0686x over previous
//
#include <hip/hip_runtime.h>
#include <hip/hip_bf16.h>

// MHSA: B=16, C=256, H=W=48, N=2304.
// S[b,n,m] = q[b,:,n]·k[b,:,m] + rhq[b][n%48][m] + rwq[b][n/48][m]
// att = softmax_m(S); out[b,c,n] = sum_m v[b,c,m] att[n,m]
//
// Logit numerics (R12): f16 (e5m10) 2-pass — K single f16 plane (quant err
// ~0.0045 logit std, 7x below R10's failed bf16-2-pass 0.031), q exact as
// f16 hi+lo: S = qh·K + ql·K. Halves S LDS reads (the dominant traffic),
// S MFMA count 768->512/block-tile, K staging bytes, and K LDS footprint.
// pos term fp32 via rank-split (f16 3-pass in k_posq). proj stays bf16 3-pass.
//
// Structure: R6-proven grid (288 blk x 8 waves x 128 rows) + __syncthreads
// sync (R9: asm grafts regress). PV n-major (R10/11). XOR swizzle everywhere.

#define BB 16
#define CC 256
#define HH 48
#define NN 2304

typedef float f32x4 __attribute__((ext_vector_type(4)));
typedef short bf16x8 __attribute__((ext_vector_type(8)));
typedef _Float16 f16x8 __attribute__((ext_vector_type(8)));

#define MFMA(a, b, c)  __builtin_amdgcn_mfma_f32_16x16x32_bf16((a), (b), (c), 0, 0, 0)
#define MFMAH(a, b, c) __builtin_amdgcn_mfma_f32_16x16x32_f16((a), (b), (c), 0, 0, 0)

__device__ inline bf16x8 ldg8(const __hip_bfloat16* p) {
    return *reinterpret_cast<const bf16x8*>(p);
}
__device__ inline f16x8 ldh8(const _Float16* p) {
    return *reinterpret_cast<const f16x8*>(p);
}

typedef __attribute__((address_space(3))) unsigned int lds_uint;
typedef const __attribute__((address_space(1))) unsigned int gbl_uint;

__device__ inline void gload_lds16(const void* g, void* l) {
    __builtin_amdgcn_global_load_lds((gbl_uint*)g, (lds_uint*)l, 16, 0, 0);
}

// ---- prep: transpose x [b][c][n] -> xT [b][n][c], split into bf16 hi/lo ----
__global__ __launch_bounds__(256) void k_prep_x(const float* __restrict__ x,
        __hip_bfloat16* __restrict__ xt_hi, __hip_bfloat16* __restrict__ xt_lo) {
    __shared__ float tile[64][65];
    int b = blockIdx.z, n0 = blockIdx.x * 64, c0 = blockIdx.y * 64;
    const float* xb = x + (size_t)b * CC * NN;
    #pragma unroll
    for (int i = 0; i < 16; ++i) {
        int idx = i * 256 + threadIdx.x;
        int r = idx >> 6, col = idx & 63;
        tile[r][col] = xb[(size_t)(c0 + r) * NN + n0 + col];
    }
    __syncthreads();
    #pragma unroll
    for (int i = 0; i < 16; ++i) {
        int idx = i * 256 + threadIdx.x;
        int r = idx >> 6, col = idx & 63;           // r = n-local, col = c-local
        float v = tile[col][r];
        __hip_bfloat16 h = __float2bfloat16(v);
        size_t o = ((size_t)b * NN + n0 + r) * CC + c0 + col;
        xt_hi[o] = h;
        xt_lo[o] = __float2bfloat16(v - __bfloat162float(h));
    }
}

// ---- prep: split Wq/Wk/Wv into hi/lo (layout [3][256][256] row-major) ----
__global__ __launch_bounds__(256) void k_prep_w(const float* __restrict__ Wq,
        const float* __restrict__ Wk, const float* __restrict__ Wv,
        __hip_bfloat16* __restrict__ w_hi, __hip_bfloat16* __restrict__ w_lo) {
    int i = blockIdx.x * 256 + threadIdx.x;         // < 3*65536
    int m = i >> 16, j = i & 65535;
    const float* W = (m == 0) ? Wq : ((m == 1) ? Wk : Wv);
    float v = W[j];
    __hip_bfloat16 h = __float2bfloat16(v);
    w_hi[i] = h;
    w_lo[i] = __float2bfloat16(v - __bfloat162float(h));
}

// ---- prep: relhT[h][c] = rel_h[c][h] etc, f16 hi/lo split ----
__global__ __launch_bounds__(256) void k_prep_rel(const float* __restrict__ rel_h,
        const float* __restrict__ rel_w,
        _Float16* __restrict__ relhT_hi, _Float16* __restrict__ relhT_lo,
        _Float16* __restrict__ relwT_hi, _Float16* __restrict__ relwT_lo) {
    int i = blockIdx.x * 256 + threadIdx.x;         // < 48*256
    int h = i >> 8, c = i & 255;
    float vh = rel_h[c * HH + h];
    float vw = rel_w[c * HH + h];
    _Float16 hh = (_Float16)vh;
    relhT_hi[i] = hh;
    relhT_lo[i] = (_Float16)(vh - (float)hh);
    _Float16 hw = (_Float16)vw;
    relwT_hi[i] = hw;
    relwT_lo[i] = (_Float16)(vw - (float)hw);
}

// ---- projection GEMM: yT[b][n][o] = sum_c xT[b][n][c] * W[o][c] + bias[o] ----
// pj=0 -> qT f16 hi/lo, pj=1 -> kT f16 single, pj=2 -> v[b][o][n] bf16
__global__ __launch_bounds__(256) void k_proj(
        const __hip_bfloat16* __restrict__ xt_hi, const __hip_bfloat16* __restrict__ xt_lo,
        const __hip_bfloat16* __restrict__ w_hi,  const __hip_bfloat16* __restrict__ w_lo,
        const float* __restrict__ bq, const float* __restrict__ bk, const float* __restrict__ bv,
        _Float16* __restrict__ qt_hi, _Float16* __restrict__ qt_lo,
        _Float16* __restrict__ kt,
        __hip_bfloat16* __restrict__ vbuf) {
    int b = blockIdx.y, pj = blockIdx.z;
    int n0 = (blockIdx.x >> 2) * 64, o0 = (blockIdx.x & 3) * 64;
    int wave = threadIdx.x >> 6, lane = threadIdx.x & 63;
    int lr = lane & 15, lg = lane >> 4;
    int rowA = n0 + wave * 16 + lr;
    const __hip_bfloat16* wh = w_hi + (size_t)pj * 65536;
    const __hip_bfloat16* wl = w_lo + (size_t)pj * 65536;
    const __hip_bfloat16* axh = xt_hi + ((size_t)b * NN + rowA) * CC;
    const __hip_bfloat16* axl = xt_lo + ((size_t)b * NN + rowA) * CC;
    f32x4 acc[4] = {};
    #pragma unroll
    for (int ks = 0; ks < 8; ++ks) {
        int kk = ks * 32 + lg * 8;
        bf16x8 ah = ldg8(axh + kk);
        bf16x8 al = ldg8(axl + kk);
        #pragma unroll
        for (int ot = 0; ot < 4; ++ot) {
            int rowB = o0 + ot * 16 + lr;
            bf16x8 bh = ldg8(wh + rowB * CC + kk);
            bf16x8 bl = ldg8(wl + rowB * CC + kk);
            acc[ot] = MFMA(ah, bh, acc[ot]);
            acc[ot] = MFMA(ah, bl, acc[ot]);
            acc[ot] = MFMA(al, bh, acc[ot]);
        }
    }
    const float* bias = (pj == 0) ? bq : ((pj == 1) ? bk : bv);
    #pragma unroll
    for (int ot = 0; ot < 4; ++ot) {
        int o = o0 + ot * 16 + lr;
        float bb = bias[o];
        #pragma unroll
        for (int r = 0; r < 4; ++r) {
            int n = n0 + wave * 16 + lg * 4 + r;
            float y = acc[ot][r] + bb;
            if (pj == 0) {
                _Float16 h = (_Float16)y;
                size_t off = ((size_t)b * NN + n) * CC + o;
                qt_hi[off] = h;
                qt_lo[off] = (_Float16)(y - (float)h);
            } else if (pj == 1) {
                kt[((size_t)b * NN + n) * CC + o] = (_Float16)y;
            } else {
                vbuf[((size_t)b * CC + o) * NN + n] = __float2bfloat16(y);
            }
        }
    }
}

// ---- pos rank-split (f16 3-pass): rhq[b][h][m] = sum_c relhT[h][c] q[b][c][m]
__global__ __launch_bounds__(256) void k_posq(
        const _Float16* __restrict__ qt_hi, const _Float16* __restrict__ qt_lo,
        const _Float16* __restrict__ relhT_hi, const _Float16* __restrict__ relhT_lo,
        const _Float16* __restrict__ relwT_hi, const _Float16* __restrict__ relwT_lo,
        float* __restrict__ rhq, float* __restrict__ rwq) {
    int b = blockIdx.y, m0 = blockIdx.x * 64;
    int wave = threadIdx.x >> 6, lane = threadIdx.x & 63;
    int lr = lane & 15, lg = lane >> 4;
    int m = m0 + wave * 16 + lr;                    // output column
    const size_t bN = (size_t)b * NN;
    f32x4 acc[6] = {};                              // 3 h-tiles rh, 3 w-tiles rw
    #pragma unroll
    for (int ks = 0; ks < 8; ++ks) {
        int kk = ks * 32 + lg * 8;
        f16x8 bhf = ldh8(qt_hi + (bN + m) * CC + kk);
        f16x8 blf = ldh8(qt_lo + (bN + m) * CC + kk);
        #pragma unroll
        for (int t = 0; t < 3; ++t) {
            int rowH = t * 16 + lr;
            f16x8 ahh = ldh8(relhT_hi + rowH * CC + kk);
            f16x8 ahl = ldh8(relhT_lo + rowH * CC + kk);
            acc[t] = MFMAH(ahh, bhf, acc[t]);
            acc[t] = MFMAH(ahl, bhf, acc[t]);
            acc[t] = MFMAH(ahh, blf, acc[t]);
            f16x8 awh = ldh8(relwT_hi + rowH * CC + kk);
            f16x8 awl = ldh8(relwT_lo + rowH * CC + kk);
            acc[3 + t] = MFMAH(awh, bhf, acc[3 + t]);
            acc[3 + t] = MFMAH(awl, bhf, acc[3 + t]);
            acc[3 + t] = MFMAH(awh, blf, acc[3 + t]);
        }
    }
    #pragma unroll
    for (int t = 0; t < 3; ++t) {
        #pragma unroll
        for (int r = 0; r < 4; ++r) {
            int h = t * 16 + lg * 4 + r;
            rhq[((size_t)b * HH + h) * NN + m] = acc[t][r];
            rwq[((size_t)b * HH + h) * NN + m] = acc[3 + t][r];
        }
    }
}

// ---- flash attention: 1 block = 128 rows (8 waves x 16), m-tiles of 64 ----
// S: wave w owns q-rows 16w.. (Q f16 hi/lo in regs, K f16 single from LDS,
// 2-pass). Softmax per S-wave; P + scale shared via LDS (scale aliased into
// dead lds_k[1]). PV n-major: wave owns [64n x 64c]. XOR swizzle everywhere.
__global__ __launch_bounds__(512, 2) void k_attn(
        const _Float16* __restrict__ qt_hi, const _Float16* __restrict__ qt_lo,
        const _Float16* __restrict__ kt,
        const float* __restrict__ rhq, const float* __restrict__ rwq,
        const __hip_bfloat16* __restrict__ vbuf, float* __restrict__ out) {
    __shared__ __align__(16) _Float16 lds_k[2][64][64];           // [buf][row][k] 16KB
    __shared__ __align__(16) __hip_bfloat16 lds_v[256][64];       // [c][m] 32KB (swizzled)
    __shared__ __align__(16) __hip_bfloat16 lds_p[128][64];       // shared P tile 16KB (swizzled)
    // scale/lrun aliased into lds_k[1]: dead from ph3-consume until next-tile
    // ph0 restage (after the PV-end barrier). 1KB of 8KB used.
    float* lds_scale = reinterpret_cast<float*>(&lds_k[1][0][0]);
    float* lds_lrun  = lds_scale + 128;
    int b = blockIdx.y;
    int n0 = blockIdx.x * 128;
    int wave = threadIdx.x >> 6, lane = threadIdx.x & 63;
    int lr = lane & 15, lg = lane >> 4;
    int rowA = n0 + wave * 16 + lr;
    const size_t bN = (size_t)b * NN;

    // Q fragments in registers: 16 rows x 256 k per wave, f16 hi+lo
    f16x8 qh[8], ql[8];
    #pragma unroll
    for (int ks = 0; ks < 8; ++ks) {
        int kk = ks * 32 + lg * 8;
        qh[ks] = ldh8(qt_hi + (bN + rowA) * CC + kk);
        ql[ks] = ldh8(qt_lo + (bN + rowA) * CC + kk);
    }
    // pos-table row indices for this lane's 4 softmax rows
    int hn[4], wn[4];
    #pragma unroll
    for (int r = 0; r < 4; ++r) {
        int n = n0 + wave * 16 + lg * 4 + r;
        hn[r] = n % HH;
        wn[r] = n / HH;
    }
    const float* rhq_b = rhq + (size_t)b * HH * NN;
    const float* rwq_b = rwq + (size_t)b * HH * NN;

    // PV ownership: [64n x 64c] per wave
    int nh = wave >> 2;                 // n-half: rows nh*64 .. +63
    int cq = wave & 3;                  // c-quarter: cols cq*64 .. +63
    f32x4 oacc[4][4] = {};              // [nf][cf]
    float mrun[4] = {-1e30f, -1e30f, -1e30f, -1e30f};
    float lrun[4] = {0.f, 0.f, 0.f, 0.f};

    // staging: LDS dest linear (lane*16B); global source chunk pre-swizzled so
    // logical chunk c of row r lands at physical chunk c^(r&7).
    int srl = lane >> 3;                      // row within wave's 8-row group
    int sch = ((lane & 7) ^ srl) * 8;         // pre-swizzled source offset (elems)
    auto STAGE_K = [&](int buf, int m0s, int k0) {
        int grow = m0s + wave * 8 + srl;
        gload_lds16(kt + (bN + grow) * CC + k0 + sch, &lds_k[buf][wave * 8][0]);
    };
    auto STAGE_V = [&](int q, int m0s) {       // quarter q: c-rows [q*64, q*64+64)
        int crow = q * 64 + wave * 8 + srl;
        gload_lds16(vbuf + ((size_t)b * CC + crow) * NN + m0s + sch, &lds_v[q * 64 + wave * 8][0]);
    };

    int cur = 0;
    STAGE_K(0, 0, 0);
    __syncthreads();

    for (int t = 0; t < 36; ++t) {
        int m0 = t * 64;
        // pos adds (issued early; consumed after 4 phases — hidden)
        float padd[4][4];
        #pragma unroll
        for (int mt = 0; mt < 4; ++mt) {
            int m = m0 + mt * 16 + lr;
            #pragma unroll
            for (int r = 0; r < 4; ++r)
                padd[mt][r] = rhq_b[(size_t)hn[r] * NN + m] + rwq_b[(size_t)wn[r] * NN + m];
        }
        // ---- S tile [16n x 64m], K=256 in 4 phases of 64, f16 2-pass ----
        // buf trace (cur=0 at tile start): ph0 reads 0 stages 1; ph1 reads 1
        // stages 0; ph2 reads 0 stages 1; ph3 reads 1 stages 0 (next tile).
        // => during PV, buf1 is dead (scale alias target), buf0 holds t+1 data.
        f32x4 sacc[4] = {};
        #pragma unroll
        for (int ph = 0; ph < 4; ++ph) {
            if (ph < 3) STAGE_K(cur ^ 1, m0, (ph + 1) * 64);
            else if (t + 1 < 36) STAGE_K(cur ^ 1, m0 + 64, 0);
            STAGE_V(ph, m0);                       // quarter ph of current tile
            #pragma unroll
            for (int ks = 0; ks < 2; ++ks) {
                #pragma unroll
                for (int mt = 0; mt < 4; ++mt) {
                    int row = mt * 16 + lr;
                    int ch = ((ks * 4 + lg) ^ (lr & 7)) * 8;   // swizzled read
                    f16x8 bh = *reinterpret_cast<const f16x8*>(&lds_k[cur][row][ch]);
                    sacc[mt] = MFMAH(qh[ph * 2 + ks], bh, sacc[mt]);
                    sacc[mt] = MFMAH(ql[ph * 2 + ks], bh, sacc[mt]);
                }
            }
            __syncthreads();
            cur ^= 1;
        }
        // ---- add pos term, online softmax (per S-wave rows) ----
        #pragma unroll
        for (int mt = 0; mt < 4; ++mt)
            #pragma unroll
            for (int r = 0; r < 4; ++r)
                sacc[mt][r] += padd[mt][r];
        float scl_r[4];
        #pragma unroll
        for (int r = 0; r < 4; ++r) {
            float smax = fmaxf(fmaxf(sacc[0][r], sacc[1][r]), fmaxf(sacc[2][r], sacc[3][r]));
            #pragma unroll
            for (int mk = 1; mk <= 8; mk <<= 1)
                smax = fmaxf(smax, __shfl_xor(smax, mk));
            float mnew = fmaxf(mrun[r], smax);
            scl_r[r] = __expf(mrun[r] - mnew);
            float rsum = 0.f;
            #pragma unroll
            for (int mt = 0; mt < 4; ++mt) {
                float p = __expf(sacc[mt][r] - mnew);
                sacc[mt][r] = p;
                rsum += p;
            }
            #pragma unroll
            for (int mk = 1; mk <= 8; mk <<= 1)
                rsum += __shfl_xor(rsum, mk);
            lrun[r] = lrun[r] * scl_r[r] + rsum;
            mrun[r] = mnew;
        }
        // ---- P + scale -> shared LDS (XOR-swizzled P; scale into dead buf1)
        #pragma unroll
        for (int mt = 0; mt < 4; ++mt) {
            #pragma unroll
            for (int r = 0; r < 4; ++r) {
                int prow = wave * 16 + lg * 4 + r;
                int pcol = mt * 16 + lr;
                int pcol_s = (((pcol >> 3) ^ (prow & 7)) << 3) | (pcol & 7);
                lds_p[prow][pcol_s] = __float2bfloat16(sacc[mt][r]);
            }
        }
        if (lr == 0) {
            #pragma unroll
            for (int r = 0; r < 4; ++r)
                lds_scale[wave * 16 + lg * 4 + r] = scl_r[r];
        }
        __syncthreads();   // P, scale, and all 4 V quarters visible
        // ---- PV: wave computes [64n x 64c]; rescale then accumulate ----
        f32x4 scl4[4];
        #pragma unroll
        for (int nf = 0; nf < 4; ++nf) {
            scl4[nf] = *reinterpret_cast<const f32x4*>(&lds_scale[nh * 64 + nf * 16 + lg * 4]);
            #pragma unroll
            for (int cf = 0; cf < 4; ++cf)
                oacc[nf][cf] *= scl4[nf];
        }
        #pragma unroll
        for (int ks2 = 0; ks2 < 2; ++ks2) {
            bf16x8 pa[4];
            #pragma unroll
            for (int nf = 0; nf < 4; ++nf) {
                int prow = nh * 64 + nf * 16 + lr;
                int pch = ((ks2 * 4 + lg) ^ (lr & 7)) * 8;
                pa[nf] = *reinterpret_cast<const bf16x8*>(&lds_p[prow][pch]);
            }
            #pragma unroll
            for (int cf = 0; cf < 4; ++cf) {
                int vrow = cq * 64 + cf * 16 + lr;
                int vch = ((ks2 * 4 + lg) ^ (lr & 7)) * 8;
                bf16x8 bv = *reinterpret_cast<const bf16x8*>(&lds_v[vrow][vch]);
                #pragma unroll
                for (int nf = 0; nf < 4; ++nf)
                    oacc[nf][cf] = MFMA(pa[nf], bv, oacc[nf][cf]);
            }
        }
        __syncthreads();   // PV reads (incl. scale in buf1) done before restage
    }
    // ---- epilogue: publish lrun (dead LDS), each PV-wave normalizes+stores
    if (lr == 0) {
        #pragma unroll
        for (int r = 0; r < 4; ++r)
            lds_lrun[wave * 16 + lg * 4 + r] = lrun[r];
    }
    __syncthreads();
    #pragma unroll
    for (int nf = 0; nf < 4; ++nf) {
        f32x4 lr4 = *reinterpret_cast<const f32x4*>(&lds_lrun[nh * 64 + nf * 16 + lg * 4]);
        int nbase = n0 + nh * 64 + nf * 16 + lg * 4;
        #pragma unroll
        for (int cf = 0; cf < 4; ++cf) {
            int c = cq * 64 + cf * 16 + lr;
            f32x4 o = oacc[nf][cf] / lr4;
            *reinterpret_cast<f32x4*>(&out[((size_t)b * CC + c) * NN + nbase]) = o;
        }
    }
}

extern "C" void kernel_launch(void* const* d_in, const int* in_sizes, int n_in,
                              void* d_out, int out_size, void* d_ws, size_t ws_size,
                              hipStream_t stream) {
    const float* x     = (const float*)d_in[0];
    const float* Wq    = (const float*)d_in[1];
    const float* bq    = (const float*)d_in[2];
    const float* Wk    = (const float*)d_in[3];
    const float* bk    = (const float*)d_in[4];
    const float* Wv    = (const float*)d_in[5];
    const float* bv    = (const float*)d_in[6];
    const float* rel_h = (const float*)d_in[7];
    const float* rel_w = (const float*)d_in[8];
    float* out = (float*)d_out;

    size_t off = 0;
    auto carve = [&](size_t bytes) {
        void* p = (char*)d_ws + off;
        off += (bytes + 255) & ~(size_t)255;
        return p;
    };
    const size_t sz_t = (size_t)BB * NN * CC * 2;   // 2B elems
    __hip_bfloat16* xt_hi  = (__hip_bfloat16*)carve(sz_t);
    __hip_bfloat16* xt_lo  = (__hip_bfloat16*)carve(sz_t);
    _Float16*       qt_hi  = (_Float16*)carve(sz_t);
    _Float16*       qt_lo  = (_Float16*)carve(sz_t);
    _Float16*       kt     = (_Float16*)carve(sz_t);
    __hip_bfloat16* vbuf   = (__hip_bfloat16*)carve(sz_t);
    _Float16* relhT_hi = (_Float16*)carve((size_t)HH * CC * 2);
    _Float16* relhT_lo = (_Float16*)carve((size_t)HH * CC * 2);
    _Float16* relwT_hi = (_Float16*)carve((size_t)HH * CC * 2);
    _Float16* relwT_lo = (_Float16*)carve((size_t)HH * CC * 2);
    __hip_bfloat16* w_hi   = (__hip_bfloat16*)carve((size_t)3 * CC * CC * 2);
    __hip_bfloat16* w_lo   = (__hip_bfloat16*)carve((size_t)3 * CC * CC * 2);
    float* rhq = (float*)carve((size_t)BB * HH * NN * 4);
    float* rwq = (float*)carve((size_t)BB * HH * NN * 4);
    if (off > ws_size) return;   // workspace too small -> output stays poisoned (visible failure)

    k_prep_x<<<dim3(NN / 64, CC / 64, BB), 256, 0, stream>>>(x, xt_hi, xt_lo);
    k_prep_w<<<dim3(3 * CC * CC / 256), 256, 0, stream>>>(Wq, Wk, Wv, w_hi, w_lo);
    k_prep_rel<<<dim3(HH * CC / 256), 256, 0, stream>>>(rel_h, rel_w,
        relhT_hi, relhT_lo, relwT_hi, relwT_lo);
    k_proj<<<dim3((NN / 64) * (CC / 64), BB, 3), 256, 0, stream>>>(
        xt_hi, xt_lo, w_hi, w_lo, bq, bk, bv, qt_hi, qt_lo, kt, vbuf);
    k_posq<<<dim3(NN / 64, BB), 256, 0, stream>>>(
        qt_hi, qt_lo, relhT_hi, relhT_lo, relwT_hi, relwT_lo, rhq, rwq);
    k_attn<<<dim3(NN / 128, BB), 512, 0, stream>>>(
        qt_hi, qt_lo, kt, rhq, rwq, vbuf, out);
}